// Round 9
// baseline (160.596 us; speedup 1.0000x reference)
//
#include <hip/hip_runtime.h>
#include <math.h>

#define B_   8
#define N_   512
#define F_   64
#define G_   64
#define M_   4
#define E_   4
#define MEG  1024

typedef __attribute__((ext_vector_type(8))) __bf16 bf16x8;
typedef __attribute__((ext_vector_type(4))) float f32x4;
typedef unsigned short ush;

static __device__ __forceinline__ ush bfu(float x) { __bf16 h = (__bf16)x; return __builtin_bit_cast(ush, h); }
static __device__ __forceinline__ bf16x8 asbf(int4 v) { return __builtin_bit_cast(bf16x8, v); }

// ---------------- kprep: all bf16 conversions / transposes / c-vectors ----------------
__global__ void __launch_bounds__(256) kprep(const float* __restrict__ X, const float* __restrict__ Ws,
                                             const float* __restrict__ a1, const float* __restrict__ a2,
                                             const float* __restrict__ W_emb1, const float* __restrict__ W2a,
                                             const float* __restrict__ W2b,
                                             ush* __restrict__ Xb, ush* __restrict__ WsT, ush* __restrict__ cpack,
                                             ush* __restrict__ W1b, ush* __restrict__ W2ab, ush* __restrict__ W2bb) {
  int idx = blockIdx.x * 256 + threadIdx.x;
  if (idx < 65536) {                       // Xb [4096][64] bf16
    float4 v = ((const float4*)X)[idx];
    ushort4 o; o.x = bfu(v.x); o.y = bfu(v.y); o.z = bfu(v.z); o.w = bfu(v.w);
    ((ushort4*)Xb)[idx] = o;
  } else if (idx < 131072) {               // WsT [em][g][f] bf16
    int j = idx - 65536; int em = j >> 12, g = (j >> 6) & 63, f = j & 63;
    WsT[j] = bfu(Ws[em * 4096 + f * 64 + g]);
  } else if (idx < 132096) {               // cpack [em][16][f]: rows 0,1 = Ws@a1, Ws@a2
    int j = idx - 131072; int em = j >> 6, f = j & 63;
    const float* wp = Ws + em * 4096 + f * 64;
    const float* p1 = a1 + em * 64; const float* p2 = a2 + em * 64;
    float c1 = 0.f, c2 = 0.f;
    for (int g = 0; g < 64; ++g) { float w = wp[g]; c1 = fmaf(w, p1[g], c1); c2 = fmaf(w, p2[g], c2); }
    cpack[em * 1024 + f] = bfu(c1);
    cpack[em * 1024 + 64 + f] = bfu(c2);
    for (int r = 2; r < 16; ++r) cpack[em * 1024 + r * 64 + f] = 0;
  } else if (idx < 148480) {               // W1b = bf16(W_emb1) [64][1024]
    int j = idx - 132096;
    float4 v = ((const float4*)W_emb1)[j];
    ushort4 o; o.x = bfu(v.x); o.y = bfu(v.y); o.z = bfu(v.z); o.w = bfu(v.w);
    ((ushort4*)W1b)[j] = o;
  } else if (idx < 152576) {               // W2ab = bf16(W2a) [256][64]
    int j = idx - 148480;
    float4 v = ((const float4*)W2a)[j];
    ushort4 o; o.x = bfu(v.x); o.y = bfu(v.y); o.z = bfu(v.z); o.w = bfu(v.w);
    ((ushort4*)W2ab)[j] = o;
  } else if (idx < 156672) {               // W2bb = bf16(W2b) [64][256]
    int j = idx - 152576;
    float4 v = ((const float4*)W2b)[j];
    ushort4 o; o.x = bfu(v.x); o.y = bfu(v.y); o.z = bfu(v.z); o.w = bfu(v.w);
    ((ushort4*)W2bb)[j] = o;
  }
}

// ---------------- K1: MFMA WhT + s1/E2; PLUS A->bitmask (overlapped stream) ----------------
__global__ void __launch_bounds__(256) k1_wh(const ush* __restrict__ Xb, const ush* __restrict__ WsT,
                                             const ush* __restrict__ cpack, const int* __restrict__ A,
                                             ush* __restrict__ WhT, float* __restrict__ s1,
                                             float2* __restrict__ E2, unsigned* __restrict__ Amask) {
  const int tid = threadIdx.x, lane = tid & 63, w = tid >> 6, c = lane & 15, grp = lane >> 4;
  const int blk = blockIdx.x, nt = blk & 7, em = (blk >> 3) & 15, b = blk >> 7;
  const int n0 = nt * 64, bem = b * 16 + em;

  // A -> bitmask: thread handles one 32-bit word; 128B contiguous read per thread.
  {
    const int w2 = blk * 256 + tid;                 // 0..262143  -> [be][i][c]
    const int* ap = A + (w2 >> 4) * 32 * 16 + (w2 & 15) * 32;
    unsigned bits = 0;
#pragma unroll
    for (int kq = 0; kq < 32; kq += 4) {
      int4 v = *(const int4*)(ap + kq);
      bits |= (v.x > 0 ? 1u : 0u) << kq;
      bits |= (v.y > 0 ? 1u : 0u) << (kq + 1);
      bits |= (v.z > 0 ? 1u : 0u) << (kq + 2);
      bits |= (v.w > 0 ? 1u : 0u) << (kq + 3);
    }
    Amask[w2] = bits;
  }

  f32x4 acc[4] = {};
  const ush* wsrow = WsT + em * 4096 + (w * 16 + c) * 64;
#pragma unroll
  for (int kk = 0; kk < 2; ++kk) {
    bf16x8 af = asbf(*(const int4*)(wsrow + kk * 32 + grp * 8));
#pragma unroll
    for (int t = 0; t < 4; ++t) {
      bf16x8 bv = asbf(*(const int4*)(Xb + (b * 512 + n0 + t * 16 + c) * 64 + kk * 32 + grp * 8));
      acc[t] = __builtin_amdgcn_mfma_f32_16x16x32_bf16(af, bv, acc[t], 0, 0, 0);
    }
  }
  ush* wout = WhT + bem * 32768;
#pragma unroll
  for (int t = 0; t < 4; ++t)
#pragma unroll
    for (int r = 0; r < 4; ++r)
      wout[(w * 16 + grp * 4 + r) * 512 + n0 + t * 16 + c] = bfu(acc[t][r]);
  if (w == 0) {                            // s1 + E2=(exp(s2), exp(.01 s2)) via cpack MFMA
    f32x4 sacc[4] = {};
    const ush* crow = cpack + em * 1024 + c * 64;
#pragma unroll
    for (int kk = 0; kk < 2; ++kk) {
      bf16x8 af = asbf(*(const int4*)(crow + kk * 32 + grp * 8));
#pragma unroll
      for (int t = 0; t < 4; ++t) {
        bf16x8 bv = asbf(*(const int4*)(Xb + (b * 512 + n0 + t * 16 + c) * 64 + kk * 32 + grp * 8));
        sacc[t] = __builtin_amdgcn_mfma_f32_16x16x32_bf16(af, bv, sacc[t], 0, 0, 0);
      }
    }
    if (grp == 0) {
#pragma unroll
      for (int t = 0; t < 4; ++t) {
        float s2v = sacc[t][1];
        s1[bem * 512 + n0 + t * 16 + c] = sacc[t][0];
        E2[bem * 512 + n0 + t * 16 + c] = make_float2(__expf(s2v), __expf(0.01f * s2v));
      }
    }
  }
}

// ---------------- K2: 8-wave (4 m x 2 j-halves) factorized softmax + MFMA PV + ELU -------
// occupancy-first: 512 thr, 4 blocks/CU -> 32 waves/CU. j-half-1 partials combined via LDS.
__global__ void __launch_bounds__(512, 8) k2_attn(const unsigned* __restrict__ Amask,
                                                  const ush* __restrict__ WhT,
                                                  const float* __restrict__ s1,
                                                  const float2* __restrict__ E2,
                                                  ush* __restrict__ Hb) {
  const int tid = threadIdx.x, lane = tid & 63, wv = tid >> 6;
  const int m = wv & 3, jh = wv >> 2;
  const int grp = lane >> 4, col = lane & 15;
  const int blk = blockIdx.x;
  const int xcd = blk & 7, kk2 = blk >> 3;
  const int be = xcd * 4 + (kk2 >> 5), itile = kk2 & 31;
  const int b = be >> 2, e = be & 3;
  const int i0 = itile * 16;
  const int bem = be * 4 + m;

  __shared__ unsigned maskw[16][17];
  __shared__ float sums_l[4][16];
  __shared__ float2 e2l[4][512];       // 16KB, shared by both j-halves of each m
  __shared__ float accb[4][64][17];    // 17.4KB: j-half-1 partials (16 acc + rsum)

  {  // load 16x16 mask words (1KB, coalesced)
    const int row = tid >> 4, c = tid & 15;
    if (tid < 256) maskw[row][c] = Amask[(be * 512 + i0 + row) * 16 + c];
  }
  {  // stage E2[bem]: each of the 8 waves loads its quarter-of-two-rows slice
    const float2* e2g = E2 + bem * 512;
#pragma unroll
    for (int t = 0; t < 4; ++t) e2l[m][jh * 256 + t * 64 + lane] = e2g[jh * 256 + t * 64 + lane];
  }
  __syncthreads();

  const float s1row = s1[bem * N_ + i0 + col];
  const float e1p = __expf(s1row);
  const float e1n = __expf(0.01f * s1row);
  const float te  = __expf(-s1row);

  const ush* whp = WhT + bem * (G_ * N_) + col * N_ + grp * 8;
  f32x4 acc0 = {0.f, 0.f, 0.f, 0.f};
  f32x4 acc1 = acc0, acc2 = acc0, acc3 = acc0;
  float rsum = 0.f;

  const int s0 = jh * 8;
  // software-pipelined over this wave's 8 iterations
  int4 c0 = *(const int4*)(whp + s0 * 32);
  int4 c1 = *(const int4*)(whp + 8192 + s0 * 32);
  int4 c2 = *(const int4*)(whp + 16384 + s0 * 32);
  int4 c3 = *(const int4*)(whp + 24576 + s0 * 32);
#pragma unroll
  for (int s = s0; s < s0 + 8; ++s) {
    const int noff = ((s + 1) & 15) * 32;          // last iter wraps (harmless cached re-load)
    int4 n0 = *(const int4*)(whp + noff);
    int4 n1 = *(const int4*)(whp + 8192 + noff);
    int4 n2 = *(const int4*)(whp + 16384 + noff);
    int4 n3 = *(const int4*)(whp + 24576 + noff);

    unsigned mb = maskw[col][s] >> (grp * 8);
    const float2* ep = &e2l[m][s * 32 + grp * 8];
    bf16x8 af;
#pragma unroll
    for (int i = 0; i < 8; ++i) {
      float2 q = ep[i];
      float p = (q.x > te) ? q.x * e1p : q.y * e1n;
      p = ((mb >> i) & 1u) ? p : 0.f;
      rsum += p;
      af[i] = (__bf16)p;
    }
    acc0 = __builtin_amdgcn_mfma_f32_16x16x32_bf16(af, asbf(c0), acc0, 0, 0, 0);
    acc1 = __builtin_amdgcn_mfma_f32_16x16x32_bf16(af, asbf(c1), acc1, 0, 0, 0);
    acc2 = __builtin_amdgcn_mfma_f32_16x16x32_bf16(af, asbf(c2), acc2, 0, 0, 0);
    acc3 = __builtin_amdgcn_mfma_f32_16x16x32_bf16(af, asbf(c3), acc3, 0, 0, 0);
    c0 = n0; c1 = n1; c2 = n2; c3 = n3;
  }

  // combine j-halves: half-1 dumps partials, half-0 adds and finishes.
  if (jh == 1) {
#pragma unroll
    for (int r = 0; r < 4; ++r) {
      accb[m][lane][r]      = acc0[r];
      accb[m][lane][4 + r]  = acc1[r];
      accb[m][lane][8 + r]  = acc2[r];
      accb[m][lane][12 + r] = acc3[r];
    }
    accb[m][lane][16] = rsum;
  }
  __syncthreads();
  if (jh == 0) {
#pragma unroll
    for (int r = 0; r < 4; ++r) {
      acc0[r] += accb[m][lane][r];
      acc1[r] += accb[m][lane][4 + r];
      acc2[r] += accb[m][lane][8 + r];
      acc3[r] += accb[m][lane][12 + r];
    }
    rsum += accb[m][lane][16];
    rsum += __shfl_xor(rsum, 16);
    rsum += __shfl_xor(rsum, 32);
    if (grp == 0) sums_l[m][col] = rsum;
  }
  __syncthreads();
  if (jh == 0) {
    ush* op = Hb + (b * N_ + i0 + grp * 4) * MEG + m * 256 + e * 64 + col;
#pragma unroll
    for (int r = 0; r < 4; ++r) {
      float sv2 = sums_l[m][grp * 4 + r];
      float inv = sv2 > 0.f ? 1.f / sv2 : 0.f;
      float v0 = acc0[r] * inv; v0 = v0 > 0.f ? v0 : expm1f(v0);
      float v1 = acc1[r] * inv; v1 = v1 > 0.f ? v1 : expm1f(v1);
      float v2 = acc2[r] * inv; v2 = v2 > 0.f ? v2 : expm1f(v2);
      float v3 = acc3[r] * inv; v3 = v3 > 0.f ? v3 : expm1f(v3);
      op[r * MEG + 0]  = bfu(v0);
      op[r * MEG + 16] = bfu(v1);
      op[r * MEG + 32] = bfu(v2);
      op[r * MEG + 48] = bfu(v3);
    }
  }
}

// ---------------- K3: MFMA  R = 0.5*(Hb @ W1b^T) + 0.5*X; partials P2R[blk][2][64] ----------------
__global__ void __launch_bounds__(256) k3_emb(const ush* __restrict__ Hb, const ush* __restrict__ W1b,
                                              const float* __restrict__ X, float* __restrict__ R,
                                              float* __restrict__ P2R) {
  const int tid = threadIdx.x, lane = tid & 63, w = tid >> 6, c = lane & 15, grp = lane >> 4;
  const int r0 = blockIdx.x * 16;
  const ush* ha = Hb + (r0 + c) * 1024 + grp * 8;
  const ush* wb = W1b + (w * 16 + c) * 1024 + grp * 8;
  f32x4 accA = {}, accB = {};      // 2 independent chains (break 32-deep MFMA dependency)
#pragma unroll 8
  for (int kk = 0; kk < 32; kk += 2) {
    accA = __builtin_amdgcn_mfma_f32_16x16x32_bf16(asbf(*(const int4*)(ha + kk * 32)),
                                                   asbf(*(const int4*)(wb + kk * 32)), accA, 0, 0, 0);
    accB = __builtin_amdgcn_mfma_f32_16x16x32_bf16(asbf(*(const int4*)(ha + kk * 32 + 32)),
                                                   asbf(*(const int4*)(wb + kk * 32 + 32)), accB, 0, 0, 0);
  }
  f32x4 acc = accA + accB;
  const int col = w * 16 + c;
  float s = 0.f, q = 0.f;
#pragma unroll
  for (int r = 0; r < 4; ++r) {
    int row = r0 + grp * 4 + r;
    float v = 0.5f * acc[r] + 0.5f * X[row * 64 + col];
    R[row * 64 + col] = v;
    s += v; q = fmaf(v, v, q);
  }
  s += __shfl_xor(s, 16); s += __shfl_xor(s, 32);
  q += __shfl_xor(q, 16); q += __shfl_xor(q, 32);
  if (grp == 0) { P2R[blockIdx.x * 128 + col] = s; P2R[blockIdx.x * 128 + 64 + col] = q; }
}

// ---------------- K4: reduce P2R -> muR/rsR (per block); T = BN(R) @ W2a^T; P2T[blk][2][256] ----
__global__ void __launch_bounds__(256) k4_node1(const float* __restrict__ R, const float* __restrict__ P2R,
                                                const ush* __restrict__ W2ab,
                                                float* __restrict__ T, float* __restrict__ P2T) {
  const int tid = threadIdx.x, lane = tid & 63, w = tid >> 6, c = lane & 15, grp = lane >> 4;
  const int r0 = blockIdx.x * 16, cb = w * 64;
  __shared__ float muR[64], rsR[64];
  if (tid < 128) {
    const int cc = tid & 63;
    float a = 0.f;
    for (int bk = 0; bk < 256; ++bk) a += P2R[bk * 128 + tid];
    if (tid < 64) muR[cc] = a * (1.f / 4096.f); else rsR[cc] = a;
  }
  __syncthreads();
  if (tid < 64) {
    float m = muR[tid];
    float v = rsR[tid] * (1.f / 4096.f) - m * m;
    rsR[tid] = rsqrtf(v + 1e-5f);
  }
  __syncthreads();

  f32x4 acc[4] = {};
#pragma unroll
  for (int kk = 0; kk < 2; ++kk) {
    const float* rp = R + (r0 + c) * 64 + kk * 32 + grp * 8;
    float4 v0 = *(const float4*)rp;
    float4 v1 = *(const float4*)(rp + 4);
    float vv[8] = {v0.x, v0.y, v0.z, v0.w, v1.x, v1.y, v1.z, v1.w};
    bf16x8 af;
#pragma unroll
    for (int i = 0; i < 8; ++i) {
      int f = kk * 32 + grp * 8 + i;
      af[i] = (__bf16)((vv[i] - muR[f]) * rsR[f]);
    }
#pragma unroll
    for (int ct = 0; ct < 4; ++ct) {
      bf16x8 bv = asbf(*(const int4*)(W2ab + (cb + ct * 16 + c) * 64 + kk * 32 + grp * 8));
      acc[ct] = __builtin_amdgcn_mfma_f32_16x16x32_bf16(af, bv, acc[ct], 0, 0, 0);
    }
  }
#pragma unroll
  for (int ct = 0; ct < 4; ++ct) {
    const int col = cb + ct * 16 + c;
    float s = 0.f, q = 0.f;
#pragma unroll
    for (int r = 0; r < 4; ++r) {
      float v = acc[ct][r];
      T[(r0 + grp * 4 + r) * 256 + col] = v;
      s += v; q = fmaf(v, v, q);
    }
    s += __shfl_xor(s, 16); s += __shfl_xor(s, 32);
    q += __shfl_xor(q, 16); q += __shfl_xor(q, 32);
    if (grp == 0) { P2T[blockIdx.x * 512 + col] = s; P2T[blockIdx.x * 512 + 256 + col] = q; }
  }
}

// ---------------- K5: reduce P2T,P2R; S = BN_R(R) + ELU(BN(T)) @ W2b^T; P2S[blk][2][64] ----------
__global__ void __launch_bounds__(256) k5_node2(const float* __restrict__ T, const float* __restrict__ P2T,
                                                const ush* __restrict__ W2bb,
                                                const float* __restrict__ R, const float* __restrict__ P2R,
                                                float* __restrict__ S, float* __restrict__ P2S) {
  const int tid = threadIdx.x, lane = tid & 63, w = tid >> 6, c = lane & 15, grp = lane >> 4;
  const int r0 = blockIdx.x * 16;
  __shared__ float muT[256], rsT[256], muR[64], rsR[64];
  {
    float s = 0.f, q = 0.f;
    for (int bk = 0; bk < 256; ++bk) {
      s += P2T[bk * 512 + tid];
      q += P2T[bk * 512 + 256 + tid];
    }
    float m = s * (1.f / 4096.f);
    float v = q * (1.f / 4096.f) - m * m;
    muT[tid] = m; rsT[tid] = rsqrtf(v + 1e-5f);
  }
  if (tid < 128) {
    const int cc = tid & 63;
    float a = 0.f;
    for (int bk = 0; bk < 256; ++bk) a += P2R[bk * 128 + tid];
    if (tid < 64) muR[cc] = a * (1.f / 4096.f); else rsR[cc] = a;
  }
  __syncthreads();
  if (tid < 64) {
    float m = muR[tid];
    float v = rsR[tid] * (1.f / 4096.f) - m * m;
    rsR[tid] = rsqrtf(v + 1e-5f);
  }
  __syncthreads();

  f32x4 accA = {}, accB = {};       // 2 independent chains
  const ush* wrow = W2bb + (w * 16 + c) * 256 + grp * 8;
  const float* trow = T + (r0 + c) * 256 + grp * 8;
#pragma unroll
  for (int kk = 0; kk < 8; ++kk) {
    float4 v0 = *(const float4*)(trow + kk * 32);
    float4 v1 = *(const float4*)(trow + kk * 32 + 4);
    float vv[8] = {v0.x, v0.y, v0.z, v0.w, v1.x, v1.y, v1.z, v1.w};
    bf16x8 af;
#pragma unroll
    for (int i = 0; i < 8; ++i) {
      int u = kk * 32 + grp * 8 + i;
      float t = (vv[i] - muT[u]) * rsT[u];
      t = t > 0.f ? t : expm1f(t);
      af[i] = (__bf16)t;
    }
    bf16x8 bv = asbf(*(const int4*)(wrow + kk * 32));
    if (kk & 1) accB = __builtin_amdgcn_mfma_f32_16x16x32_bf16(af, bv, accB, 0, 0, 0);
    else        accA = __builtin_amdgcn_mfma_f32_16x16x32_bf16(af, bv, accA, 0, 0, 0);
  }
  f32x4 acc = accA + accB;
  const int col = w * 16 + c;
  const float mu = muR[col], rsv = rsR[col];
  float s = 0.f, q = 0.f;
#pragma unroll
  for (int r = 0; r < 4; ++r) {
    int row = r0 + grp * 4 + r;
    float v = acc[r] + (R[row * 64 + col] - mu) * rsv;
    S[row * 64 + col] = v;
    s += v; q = fmaf(v, v, q);
  }
  s += __shfl_xor(s, 16); s += __shfl_xor(s, 32);
  q += __shfl_xor(q, 16); q += __shfl_xor(q, 32);
  if (grp == 0) { P2S[blockIdx.x * 128 + col] = s; P2S[blockIdx.x * 128 + 64 + col] = q; }
}

// ---------------- K6: reduce P2S; out = BN(S) ----------------
__global__ void __launch_bounds__(256) k6_bn(const float* __restrict__ S, const float* __restrict__ P2S,
                                             float* __restrict__ out) {
  const int tid = threadIdx.x;
  const int r0 = blockIdx.x * 16;
  __shared__ float muS[64], rsS[64];
  if (tid < 128) {
    const int cc = tid & 63;
    float a = 0.f;
    for (int bk = 0; bk < 256; ++bk) a += P2S[bk * 128 + tid];
    if (tid < 64) muS[cc] = a * (1.f / 4096.f); else rsS[cc] = a;
  }
  __syncthreads();
  if (tid < 64) {
    float m = muS[tid];
    float v = rsS[tid] * (1.f / 4096.f) - m * m;
    rsS[tid] = rsqrtf(v + 1e-5f);
  }
  __syncthreads();
  const int f0 = (tid * 4) & 63;
  float4 v = *(const float4*)(S + r0 * 64 + tid * 4);
  float4 o;
  o.x = (v.x - muS[f0 + 0]) * rsS[f0 + 0];
  o.y = (v.y - muS[f0 + 1]) * rsS[f0 + 1];
  o.z = (v.z - muS[f0 + 2]) * rsS[f0 + 2];
  o.w = (v.w - muS[f0 + 3]) * rsS[f0 + 3];
  *(float4*)(out + r0 * 64 + tid * 4) = o;
}

extern "C" void kernel_launch(void* const* d_in, const int* in_sizes, int n_in,
                              void* d_out, int out_size, void* d_ws, size_t ws_size,
                              hipStream_t stream) {
  const int*   A      = (const int*)d_in[0];
  const float* X      = (const float*)d_in[1];
  const float* Ws     = (const float*)d_in[2];
  const float* a1     = (const float*)d_in[3];
  const float* a2     = (const float*)d_in[4];
  const float* W_emb1 = (const float*)d_in[5];
  const float* W2a    = (const float*)d_in[6];
  const float* W2b    = (const float*)d_in[7];
  float* out = (float*)d_out;

  float* ws = (float*)d_ws;
  ush*   Hb    = (ush*)d_ws;                 // [4096][1024] bf16   (2,097,152 fl)
  ush*   WhT   = (ush*)(ws + 2097152);       // [128][64][512] bf16 (2,097,152 fl)
  float* s1    = ws + 4194304;               // 65,536
  float2* E2   = (float2*)(ws + 4259840);    // [128][512] float2 = 131,072 fl
  ush*   Xb    = (ush*)(ws + 4390912);       // 131,072 fl
  ush*   WsT   = (ush*)(ws + 4521984);       // 32,768 fl
  ush*   cpack = (ush*)(ws + 4554752);       // 8,192 fl
  ush*   W1b   = (ush*)(ws + 4562944);       // 32,768 fl
  ush*   W2ab  = (ush*)(ws + 4595712);       // 8,192 fl
  ush*   W2bb  = (ush*)(ws + 4603904);       // 8,192 fl
  float* R     = ws + 4612096;               // 262,144
  float* T     = ws + 4874240;               // 1,048,576
  float* S     = ws + 5922816;               // 262,144
  float* P2R   = ws + 6184960;               // 32,768  [256][2][64]
  float* P2T   = ws + 6217728;               // 131,072 [256][2][256]
  float* P2S   = ws + 6348800;               // 32,768  [256][2][64]  (end ~25.5 MB)
  // Amask [32 be][512 i][16 c] uint = 262,144 words; aliases R (R written only in k3,
  // after k2 has consumed Amask). No workspace growth.
  unsigned* Amask = (unsigned*)R;

  kprep<<<612, 256, 0, stream>>>(X, Ws, a1, a2, W_emb1, W2a, W2b, Xb, WsT, cpack, W1b, W2ab, W2bb);
  k1_wh<<<1024, 256, 0, stream>>>(Xb, WsT, cpack, A, WhT, s1, E2, Amask);
  k2_attn<<<1024, 512, 0, stream>>>(Amask, WhT, s1, E2, Hb);
  k3_emb<<<256, 256, 0, stream>>>(Hb, W1b, X, R, P2R);
  k4_node1<<<256, 256, 0, stream>>>(R, P2R, W2ab, T, P2T);
  k5_node2<<<256, 256, 0, stream>>>(T, P2T, W2bb, R, P2R, S, P2S);
  k6_bn<<<256, 256, 0, stream>>>(S, P2S, out);
}

// Round 10
// 130.883 us; speedup vs baseline: 1.2270x; 1.2270x over previous
//
#include <hip/hip_runtime.h>
#include <math.h>

#define B_   8
#define N_   512
#define F_   64
#define G_   64
#define M_   4
#define E_   4
#define MEG  1024

typedef __attribute__((ext_vector_type(8))) __bf16 bf16x8;
typedef __attribute__((ext_vector_type(4))) float f32x4;
typedef unsigned short ush;

static __device__ __forceinline__ ush bfu(float x) { __bf16 h = (__bf16)x; return __builtin_bit_cast(ush, h); }
static __device__ __forceinline__ bf16x8 asbf(int4 v) { return __builtin_bit_cast(bf16x8, v); }

// ---------------- kprep: all bf16 conversions / transposes / c-vectors ----------------
__global__ void __launch_bounds__(256) kprep(const float* __restrict__ X, const float* __restrict__ Ws,
                                             const float* __restrict__ a1, const float* __restrict__ a2,
                                             const float* __restrict__ W_emb1, const float* __restrict__ W2a,
                                             const float* __restrict__ W2b,
                                             ush* __restrict__ Xb, ush* __restrict__ WsT, ush* __restrict__ cpack,
                                             ush* __restrict__ W1b, ush* __restrict__ W2ab, ush* __restrict__ W2bb) {
  int idx = blockIdx.x * 256 + threadIdx.x;
  if (idx < 65536) {                       // Xb [4096][64] bf16
    float4 v = ((const float4*)X)[idx];
    ushort4 o; o.x = bfu(v.x); o.y = bfu(v.y); o.z = bfu(v.z); o.w = bfu(v.w);
    ((ushort4*)Xb)[idx] = o;
  } else if (idx < 131072) {               // WsT [em][g][f] bf16
    int j = idx - 65536; int em = j >> 12, g = (j >> 6) & 63, f = j & 63;
    WsT[j] = bfu(Ws[em * 4096 + f * 64 + g]);
  } else if (idx < 132096) {               // cpack [em][16][f]: rows 0,1 = Ws@a1, Ws@a2
    int j = idx - 131072; int em = j >> 6, f = j & 63;
    const float* wp = Ws + em * 4096 + f * 64;
    const float* p1 = a1 + em * 64; const float* p2 = a2 + em * 64;
    float c1 = 0.f, c2 = 0.f;
    for (int g = 0; g < 64; ++g) { float w = wp[g]; c1 = fmaf(w, p1[g], c1); c2 = fmaf(w, p2[g], c2); }
    cpack[em * 1024 + f] = bfu(c1);
    cpack[em * 1024 + 64 + f] = bfu(c2);
    for (int r = 2; r < 16; ++r) cpack[em * 1024 + r * 64 + f] = 0;
  } else if (idx < 148480) {               // W1b = bf16(W_emb1) [64][1024]
    int j = idx - 132096;
    float4 v = ((const float4*)W_emb1)[j];
    ushort4 o; o.x = bfu(v.x); o.y = bfu(v.y); o.z = bfu(v.z); o.w = bfu(v.w);
    ((ushort4*)W1b)[j] = o;
  } else if (idx < 152576) {               // W2ab = bf16(W2a) [256][64]
    int j = idx - 148480;
    float4 v = ((const float4*)W2a)[j];
    ushort4 o; o.x = bfu(v.x); o.y = bfu(v.y); o.z = bfu(v.z); o.w = bfu(v.w);
    ((ushort4*)W2ab)[j] = o;
  } else if (idx < 156672) {               // W2bb = bf16(W2b) [64][256]
    int j = idx - 152576;
    float4 v = ((const float4*)W2b)[j];
    ushort4 o; o.x = bfu(v.x); o.y = bfu(v.y); o.z = bfu(v.z); o.w = bfu(v.w);
    ((ushort4*)W2bb)[j] = o;
  }
}

// ---------------- K1: MFMA WhT + s1/s2; PLUS A->bitmask (overlapped stream) ----------------
__global__ void __launch_bounds__(256) k1_wh(const ush* __restrict__ Xb, const ush* __restrict__ WsT,
                                             const ush* __restrict__ cpack, const int* __restrict__ A,
                                             ush* __restrict__ WhT, float* __restrict__ s1,
                                             float* __restrict__ s2, unsigned* __restrict__ Amask) {
  const int tid = threadIdx.x, lane = tid & 63, w = tid >> 6, c = lane & 15, grp = lane >> 4;
  const int blk = blockIdx.x, nt = blk & 7, em = (blk >> 3) & 15, b = blk >> 7;
  const int n0 = nt * 64, bem = b * 16 + em;

  // A -> bitmask: thread handles one 32-bit word; 128B contiguous read per thread.
  {
    const int w2 = blk * 256 + tid;                 // 0..262143  -> [be][i][c]
    const int* ap = A + (w2 >> 4) * 32 * 16 + (w2 & 15) * 32;
    unsigned bits = 0;
#pragma unroll
    for (int kq = 0; kq < 32; kq += 4) {
      int4 v = *(const int4*)(ap + kq);
      bits |= (v.x > 0 ? 1u : 0u) << kq;
      bits |= (v.y > 0 ? 1u : 0u) << (kq + 1);
      bits |= (v.z > 0 ? 1u : 0u) << (kq + 2);
      bits |= (v.w > 0 ? 1u : 0u) << (kq + 3);
    }
    Amask[w2] = bits;
  }

  f32x4 acc[4] = {};
  const ush* wsrow = WsT + em * 4096 + (w * 16 + c) * 64;
#pragma unroll
  for (int kk = 0; kk < 2; ++kk) {
    bf16x8 af = asbf(*(const int4*)(wsrow + kk * 32 + grp * 8));
#pragma unroll
    for (int t = 0; t < 4; ++t) {
      bf16x8 bv = asbf(*(const int4*)(Xb + (b * 512 + n0 + t * 16 + c) * 64 + kk * 32 + grp * 8));
      acc[t] = __builtin_amdgcn_mfma_f32_16x16x32_bf16(af, bv, acc[t], 0, 0, 0);
    }
  }
  ush* wout = WhT + bem * 32768;
#pragma unroll
  for (int t = 0; t < 4; ++t)
#pragma unroll
    for (int r = 0; r < 4; ++r)
      wout[(w * 16 + grp * 4 + r) * 512 + n0 + t * 16 + c] = bfu(acc[t][r]);
  if (w == 0) {                            // s1/s2: rows 0,1 of cpack·X^T
    f32x4 sacc[4] = {};
    const ush* crow = cpack + em * 1024 + c * 64;
#pragma unroll
    for (int kk = 0; kk < 2; ++kk) {
      bf16x8 af = asbf(*(const int4*)(crow + kk * 32 + grp * 8));
#pragma unroll
      for (int t = 0; t < 4; ++t) {
        bf16x8 bv = asbf(*(const int4*)(Xb + (b * 512 + n0 + t * 16 + c) * 64 + kk * 32 + grp * 8));
        sacc[t] = __builtin_amdgcn_mfma_f32_16x16x32_bf16(af, bv, sacc[t], 0, 0, 0);
      }
    }
    if (grp == 0) {
#pragma unroll
      for (int t = 0; t < 4; ++t) {
        s1[bem * 512 + n0 + t * 16 + c] = sacc[t][0];
        s2[bem * 512 + n0 + t * 16 + c] = sacc[t][1];
      }
    }
  }
}

// ---------------- kP: materialize P[bem][i][j] bf16 (masked exp(leaky)) + Prsum -------------
// block = (bem, itile16); wave handles 4 rows; lane owns j = lane*8..+8 (s2 kept in regs).
__global__ void __launch_bounds__(256) kp_p(const float* __restrict__ s1,
                                            const float* __restrict__ s2,
                                            const unsigned* __restrict__ Amask,
                                            ush* __restrict__ P, float* __restrict__ Prsum) {
  const int tid = threadIdx.x, lane = tid & 63, wv = tid >> 6;
  const int blk = blockIdx.x;
  const int bem = blk >> 5, it = blk & 31;
  const int be = bem >> 2;
  float4 sa = *(const float4*)(s2 + bem * 512 + lane * 8);
  float4 sb = *(const float4*)(s2 + bem * 512 + lane * 8 + 4);
  const float s2r[8] = {sa.x, sa.y, sa.z, sa.w, sb.x, sb.y, sb.z, sb.w};
#pragma unroll
  for (int rl = 0; rl < 4; ++rl) {
    const int i = it * 16 + wv * 4 + rl;
    const float s1v = s1[bem * 512 + i];
    const unsigned mw = Amask[(be * 512 + i) * 16 + (lane >> 2)] >> ((lane & 3) * 8);
    unsigned wpk[4];
    float rsum = 0.f;
#pragma unroll
    for (int jj = 0; jj < 4; ++jj) {
      float x0 = s1v + s2r[2 * jj];
      float x1 = s1v + s2r[2 * jj + 1];
      x0 = x0 > 0.f ? x0 : 0.01f * x0;
      x1 = x1 > 0.f ? x1 : 0.01f * x1;
      float p0 = ((mw >> (2 * jj)) & 1u) ? __expf(x0) : 0.f;
      float p1 = ((mw >> (2 * jj + 1)) & 1u) ? __expf(x1) : 0.f;
      rsum += p0 + p1;
      wpk[jj] = (unsigned)bfu(p0) | ((unsigned)bfu(p1) << 16);
    }
    int4 o = {(int)wpk[0], (int)wpk[1], (int)wpk[2], (int)wpk[3]};
    *(int4*)(P + (bem * 512 + i) * 512 + lane * 8) = o;
#pragma unroll
    for (int off = 1; off < 64; off <<= 1) rsum += __shfl_xor(rsum, off);
    if (lane == 0) Prsum[bem * 512 + i] = rsum;
  }
}

// ---------------- K2: pure streaming GEMM  H = ELU((P @ WhT^T) / rsum) -> Hb bf16 ---------
// No LDS, no syncthreads. XCD-swizzled so WhT slice is L2-resident per XCD.
__global__ void __launch_bounds__(256) k2_attn(const ush* __restrict__ P,
                                               const float* __restrict__ Prsum,
                                               const ush* __restrict__ WhT,
                                               ush* __restrict__ Hb) {
  const int tid = threadIdx.x, lane = tid & 63, m = tid >> 6;
  const int grp = lane >> 4, col = lane & 15;
  const int blk = blockIdx.x;
  const int xcd = blk & 7, kk2 = blk >> 3;
  const int be = xcd * 4 + (kk2 >> 5), itile = kk2 & 31;
  const int b = be >> 2, e = be & 3;
  const int i0 = itile * 16;
  const int bem = be * 4 + m;

  const ush* pp  = P + (bem * 512 + i0 + col) * 512 + grp * 8;
  const ush* whp = WhT + bem * 32768 + col * 512 + grp * 8;
  f32x4 acc0 = {0.f, 0.f, 0.f, 0.f};
  f32x4 acc1 = acc0, acc2 = acc0, acc3 = acc0;

  int4 pa = *(const int4*)(pp);
  int4 c0 = *(const int4*)(whp);
  int4 c1 = *(const int4*)(whp + 8192);
  int4 c2 = *(const int4*)(whp + 16384);
  int4 c3 = *(const int4*)(whp + 24576);
#pragma unroll 4
  for (int s = 0; s < 16; ++s) {
    const int noff = ((s + 1) & 15) * 32;          // last iter wraps (harmless cached re-load)
    int4 na = *(const int4*)(pp + noff);
    int4 n0 = *(const int4*)(whp + noff);
    int4 n1 = *(const int4*)(whp + 8192 + noff);
    int4 n2 = *(const int4*)(whp + 16384 + noff);
    int4 n3 = *(const int4*)(whp + 24576 + noff);
    bf16x8 af = asbf(pa);
    acc0 = __builtin_amdgcn_mfma_f32_16x16x32_bf16(af, asbf(c0), acc0, 0, 0, 0);
    acc1 = __builtin_amdgcn_mfma_f32_16x16x32_bf16(af, asbf(c1), acc1, 0, 0, 0);
    acc2 = __builtin_amdgcn_mfma_f32_16x16x32_bf16(af, asbf(c2), acc2, 0, 0, 0);
    acc3 = __builtin_amdgcn_mfma_f32_16x16x32_bf16(af, asbf(c3), acc3, 0, 0, 0);
    pa = na; c0 = n0; c1 = n1; c2 = n2; c3 = n3;
  }

  ush* op = Hb + (b * N_ + i0 + grp * 4) * MEG + m * 256 + e * 64 + col;
  const float* rsp = Prsum + bem * 512 + i0 + grp * 4;
#pragma unroll
  for (int r = 0; r < 4; ++r) {
    float sv2 = rsp[r];
    float inv = sv2 > 0.f ? 1.f / sv2 : 0.f;
    float v0 = acc0[r] * inv; v0 = v0 > 0.f ? v0 : expm1f(v0);
    float v1 = acc1[r] * inv; v1 = v1 > 0.f ? v1 : expm1f(v1);
    float v2 = acc2[r] * inv; v2 = v2 > 0.f ? v2 : expm1f(v2);
    float v3 = acc3[r] * inv; v3 = v3 > 0.f ? v3 : expm1f(v3);
    op[r * MEG + 0]  = bfu(v0);
    op[r * MEG + 16] = bfu(v1);
    op[r * MEG + 32] = bfu(v2);
    op[r * MEG + 48] = bfu(v3);
  }
}

// ---------------- K3: MFMA  R = 0.5*(Hb @ W1b^T) + 0.5*X; partials P2R[blk][2][64] ----------------
__global__ void __launch_bounds__(256) k3_emb(const ush* __restrict__ Hb, const ush* __restrict__ W1b,
                                              const float* __restrict__ X, float* __restrict__ R,
                                              float* __restrict__ P2R) {
  const int tid = threadIdx.x, lane = tid & 63, w = tid >> 6, c = lane & 15, grp = lane >> 4;
  const int r0 = blockIdx.x * 16;
  const ush* ha = Hb + (r0 + c) * 1024 + grp * 8;
  const ush* wb = W1b + (w * 16 + c) * 1024 + grp * 8;
  f32x4 accA = {}, accB = {};      // 2 independent chains (break 32-deep MFMA dependency)
#pragma unroll 8
  for (int kk = 0; kk < 32; kk += 2) {
    accA = __builtin_amdgcn_mfma_f32_16x16x32_bf16(asbf(*(const int4*)(ha + kk * 32)),
                                                   asbf(*(const int4*)(wb + kk * 32)), accA, 0, 0, 0);
    accB = __builtin_amdgcn_mfma_f32_16x16x32_bf16(asbf(*(const int4*)(ha + kk * 32 + 32)),
                                                   asbf(*(const int4*)(wb + kk * 32 + 32)), accB, 0, 0, 0);
  }
  f32x4 acc = accA + accB;
  const int col = w * 16 + c;
  float s = 0.f, q = 0.f;
#pragma unroll
  for (int r = 0; r < 4; ++r) {
    int row = r0 + grp * 4 + r;
    float v = 0.5f * acc[r] + 0.5f * X[row * 64 + col];
    R[row * 64 + col] = v;
    s += v; q = fmaf(v, v, q);
  }
  s += __shfl_xor(s, 16); s += __shfl_xor(s, 32);
  q += __shfl_xor(q, 16); q += __shfl_xor(q, 32);
  if (grp == 0) { P2R[blockIdx.x * 128 + col] = s; P2R[blockIdx.x * 128 + 64 + col] = q; }
}

// ---------------- K4: reduce P2R -> muR/rsR (per block); T = BN(R) @ W2a^T; P2T[blk][2][256] ----
__global__ void __launch_bounds__(256) k4_node1(const float* __restrict__ R, const float* __restrict__ P2R,
                                                const ush* __restrict__ W2ab,
                                                float* __restrict__ T, float* __restrict__ P2T) {
  const int tid = threadIdx.x, lane = tid & 63, w = tid >> 6, c = lane & 15, grp = lane >> 4;
  const int r0 = blockIdx.x * 16, cb = w * 64;
  __shared__ float muR[64], rsR[64];
  if (tid < 128) {
    const int cc = tid & 63;
    float a = 0.f;
    for (int bk = 0; bk < 256; ++bk) a += P2R[bk * 128 + tid];
    if (tid < 64) muR[cc] = a * (1.f / 4096.f); else rsR[cc] = a;
  }
  __syncthreads();
  if (tid < 64) {
    float m = muR[tid];
    float v = rsR[tid] * (1.f / 4096.f) - m * m;
    rsR[tid] = rsqrtf(v + 1e-5f);
  }
  __syncthreads();

  f32x4 acc[4] = {};
#pragma unroll
  for (int kk = 0; kk < 2; ++kk) {
    const float* rp = R + (r0 + c) * 64 + kk * 32 + grp * 8;
    float4 v0 = *(const float4*)rp;
    float4 v1 = *(const float4*)(rp + 4);
    float vv[8] = {v0.x, v0.y, v0.z, v0.w, v1.x, v1.y, v1.z, v1.w};
    bf16x8 af;
#pragma unroll
    for (int i = 0; i < 8; ++i) {
      int f = kk * 32 + grp * 8 + i;
      af[i] = (__bf16)((vv[i] - muR[f]) * rsR[f]);
    }
#pragma unroll
    for (int ct = 0; ct < 4; ++ct) {
      bf16x8 bv = asbf(*(const int4*)(W2ab + (cb + ct * 16 + c) * 64 + kk * 32 + grp * 8));
      acc[ct] = __builtin_amdgcn_mfma_f32_16x16x32_bf16(af, bv, acc[ct], 0, 0, 0);
    }
  }
#pragma unroll
  for (int ct = 0; ct < 4; ++ct) {
    const int col = cb + ct * 16 + c;
    float s = 0.f, q = 0.f;
#pragma unroll
    for (int r = 0; r < 4; ++r) {
      float v = acc[ct][r];
      T[(r0 + grp * 4 + r) * 256 + col] = v;
      s += v; q = fmaf(v, v, q);
    }
    s += __shfl_xor(s, 16); s += __shfl_xor(s, 32);
    q += __shfl_xor(q, 16); q += __shfl_xor(q, 32);
    if (grp == 0) { P2T[blockIdx.x * 512 + col] = s; P2T[blockIdx.x * 512 + 256 + col] = q; }
  }
}

// ---------------- K5: reduce P2T,P2R; S = BN_R(R) + ELU(BN(T)) @ W2b^T; P2S[blk][2][64] ----------
__global__ void __launch_bounds__(256) k5_node2(const float* __restrict__ T, const float* __restrict__ P2T,
                                                const ush* __restrict__ W2bb,
                                                const float* __restrict__ R, const float* __restrict__ P2R,
                                                float* __restrict__ S, float* __restrict__ P2S) {
  const int tid = threadIdx.x, lane = tid & 63, w = tid >> 6, c = lane & 15, grp = lane >> 4;
  const int r0 = blockIdx.x * 16;
  __shared__ float muT[256], rsT[256], muR[64], rsR[64];
  {
    float s = 0.f, q = 0.f;
    for (int bk = 0; bk < 256; ++bk) {
      s += P2T[bk * 512 + tid];
      q += P2T[bk * 512 + 256 + tid];
    }
    float m = s * (1.f / 4096.f);
    float v = q * (1.f / 4096.f) - m * m;
    muT[tid] = m; rsT[tid] = rsqrtf(v + 1e-5f);
  }
  if (tid < 128) {
    const int cc = tid & 63;
    float a = 0.f;
    for (int bk = 0; bk < 256; ++bk) a += P2R[bk * 128 + tid];
    if (tid < 64) muR[cc] = a * (1.f / 4096.f); else rsR[cc] = a;
  }
  __syncthreads();
  if (tid < 64) {
    float m = muR[tid];
    float v = rsR[tid] * (1.f / 4096.f) - m * m;
    rsR[tid] = rsqrtf(v + 1e-5f);
  }
  __syncthreads();

  f32x4 accA = {}, accB = {};       // 2 independent chains
  const ush* wrow = W2bb + (w * 16 + c) * 256 + grp * 8;
  const float* trow = T + (r0 + c) * 256 + grp * 8;
#pragma unroll
  for (int kk = 0; kk < 8; ++kk) {
    float4 v0 = *(const float4*)(trow + kk * 32);
    float4 v1 = *(const float4*)(trow + kk * 32 + 4);
    float vv[8] = {v0.x, v0.y, v0.z, v0.w, v1.x, v1.y, v1.z, v1.w};
    bf16x8 af;
#pragma unroll
    for (int i = 0; i < 8; ++i) {
      int u = kk * 32 + grp * 8 + i;
      float t = (vv[i] - muT[u]) * rsT[u];
      t = t > 0.f ? t : expm1f(t);
      af[i] = (__bf16)t;
    }
    bf16x8 bv = asbf(*(const int4*)(wrow + kk * 32));
    if (kk & 1) accB = __builtin_amdgcn_mfma_f32_16x16x32_bf16(af, bv, accB, 0, 0, 0);
    else        accA = __builtin_amdgcn_mfma_f32_16x16x32_bf16(af, bv, accA, 0, 0, 0);
  }
  f32x4 acc = accA + accB;
  const int col = w * 16 + c;
  const float mu = muR[col], rsv = rsR[col];
  float s = 0.f, q = 0.f;
#pragma unroll
  for (int r = 0; r < 4; ++r) {
    int row = r0 + grp * 4 + r;
    float v = acc[r] + (R[row * 64 + col] - mu) * rsv;
    S[row * 64 + col] = v;
    s += v; q = fmaf(v, v, q);
  }
  s += __shfl_xor(s, 16); s += __shfl_xor(s, 32);
  q += __shfl_xor(q, 16); q += __shfl_xor(q, 32);
  if (grp == 0) { P2S[blockIdx.x * 128 + col] = s; P2S[blockIdx.x * 128 + 64 + col] = q; }
}

// ---------------- K6: reduce P2S; out = BN(S) ----------------
__global__ void __launch_bounds__(256) k6_bn(const float* __restrict__ S, const float* __restrict__ P2S,
                                             float* __restrict__ out) {
  const int tid = threadIdx.x;
  const int r0 = blockIdx.x * 16;
  __shared__ float muS[64], rsS[64];
  if (tid < 128) {
    const int cc = tid & 63;
    float a = 0.f;
    for (int bk = 0; bk < 256; ++bk) a += P2S[bk * 128 + tid];
    if (tid < 64) muS[cc] = a * (1.f / 4096.f); else rsS[cc] = a;
  }
  __syncthreads();
  if (tid < 64) {
    float m = muS[tid];
    float v = rsS[tid] * (1.f / 4096.f) - m * m;
    rsS[tid] = rsqrtf(v + 1e-5f);
  }
  __syncthreads();
  const int f0 = (tid * 4) & 63;
  float4 v = *(const float4*)(S + r0 * 64 + tid * 4);
  float4 o;
  o.x = (v.x - muS[f0 + 0]) * rsS[f0 + 0];
  o.y = (v.y - muS[f0 + 1]) * rsS[f0 + 1];
  o.z = (v.z - muS[f0 + 2]) * rsS[f0 + 2];
  o.w = (v.w - muS[f0 + 3]) * rsS[f0 + 3];
  *(float4*)(out + r0 * 64 + tid * 4) = o;
}

extern "C" void kernel_launch(void* const* d_in, const int* in_sizes, int n_in,
                              void* d_out, int out_size, void* d_ws, size_t ws_size,
                              hipStream_t stream) {
  const int*   A      = (const int*)d_in[0];
  const float* X      = (const float*)d_in[1];
  const float* Ws     = (const float*)d_in[2];
  const float* a1     = (const float*)d_in[3];
  const float* a2     = (const float*)d_in[4];
  const float* W_emb1 = (const float*)d_in[5];
  const float* W2a    = (const float*)d_in[6];
  const float* W2b    = (const float*)d_in[7];
  float* out = (float*)d_out;

  float* ws = (float*)d_ws;
  ush*   Hb    = (ush*)d_ws;                 // [4096][1024] bf16   (2,097,152 fl)
  ush*   WhT   = (ush*)(ws + 2097152);       // [128][64][512] bf16 (2,097,152 fl)
  float* s1    = ws + 4194304;               // 65,536
  float* s2    = ws + 4259840;               // 65,536
  ush*   Xb    = (ush*)(ws + 4325376);       // 131,072 fl
  ush*   WsT   = (ush*)(ws + 4456448);       // 32,768 fl
  ush*   cpack = (ush*)(ws + 4489216);       // 8,192 fl
  ush*   W1b   = (ush*)(ws + 4497408);       // 32,768 fl
  ush*   W2ab  = (ush*)(ws + 4530176);       // 8,192 fl
  ush*   W2bb  = (ush*)(ws + 4538368);       // 8,192 fl
  float* R     = ws + 4546560;               // 262,144
  float* T     = ws + 4808704;               // 1,048,576
  float* S     = ws + 5857280;               // 262,144
  float* P2R   = ws + 6119424;               // 32,768  [256][2][64]
  float* P2T   = ws + 6152192;               // 131,072 [256][2][256]
  float* P2S   = ws + 6283264;               // 32,768  [256][2][64]
  float* Prsum = ws + 6316032;               // 65,536  [128][512]
  ush*   Pm    = (ush*)(ws + 6381568);       // [128][512][512] bf16 = 16,777,216 fl
                                             // end 23,158,784 fl ~= 92.6 MB (ws = 256 MiB per
                                             // the harness's 262144-KB poison fill)
  // Amask [32 be][512 i][16 c] uint = 262,144 words; aliases R (R written only in k3,
  // after kp_p/k2 have consumed Amask).
  unsigned* Amask = (unsigned*)R;

  kprep<<<612, 256, 0, stream>>>(X, Ws, a1, a2, W_emb1, W2a, W2b, Xb, WsT, cpack, W1b, W2ab, W2bb);
  k1_wh<<<1024, 256, 0, stream>>>(Xb, WsT, cpack, A, WhT, s1, s2, Amask);
  kp_p<<<4096, 256, 0, stream>>>(s1, s2, Amask, Pm, Prsum);
  k2_attn<<<1024, 256, 0, stream>>>(Pm, Prsum, WhT, Hb);
  k3_emb<<<256, 256, 0, stream>>>(Hb, W1b, X, R, P2R);
  k4_node1<<<256, 256, 0, stream>>>(R, P2R, W2ab, T, P2T);
  k5_node2<<<256, 256, 0, stream>>>(T, P2T, W2bb, R, P2R, S, P2S);
  k6_bn<<<256, 256, 0, stream>>>(S, P2S, out);
}

// Round 11
// 97.105 us; speedup vs baseline: 1.6538x; 1.3479x over previous
//
#include <hip/hip_runtime.h>
#include <math.h>

#define B_   8
#define N_   512
#define F_   64
#define G_   64
#define M_   4
#define E_   4
#define MEG  1024

typedef __attribute__((ext_vector_type(8))) __bf16 bf16x8;
typedef __attribute__((ext_vector_type(4))) float f32x4;
typedef unsigned short ush;

static __device__ __forceinline__ ush bfu(float x) { __bf16 h = (__bf16)x; return __builtin_bit_cast(ush, h); }
static __device__ __forceinline__ bf16x8 asbf(int4 v) { return __builtin_bit_cast(bf16x8, v); }

// ---------------- kprep: all bf16 conversions / transposes / c-vectors ----------------
__global__ void __launch_bounds__(256) kprep(const float* __restrict__ X, const float* __restrict__ Ws,
                                             const float* __restrict__ a1, const float* __restrict__ a2,
                                             const float* __restrict__ W_emb1, const float* __restrict__ W2a,
                                             const float* __restrict__ W2b,
                                             ush* __restrict__ Xb, ush* __restrict__ WsT, ush* __restrict__ cpack,
                                             ush* __restrict__ W1b, ush* __restrict__ W2ab, ush* __restrict__ W2bb) {
  int idx = blockIdx.x * 256 + threadIdx.x;
  if (idx < 65536) {                       // Xb [4096][64] bf16
    float4 v = ((const float4*)X)[idx];
    ushort4 o; o.x = bfu(v.x); o.y = bfu(v.y); o.z = bfu(v.z); o.w = bfu(v.w);
    ((ushort4*)Xb)[idx] = o;
  } else if (idx < 131072) {               // WsT [em][g][f] bf16
    int j = idx - 65536; int em = j >> 12, g = (j >> 6) & 63, f = j & 63;
    WsT[j] = bfu(Ws[em * 4096 + f * 64 + g]);
  } else if (idx < 132096) {               // cpack [em][16][f]: rows 0,1 = Ws@a1, Ws@a2
    int j = idx - 131072; int em = j >> 6, f = j & 63;
    const float* wp = Ws + em * 4096 + f * 64;
    const float* p1 = a1 + em * 64; const float* p2 = a2 + em * 64;
    float c1 = 0.f, c2 = 0.f;
    for (int g = 0; g < 64; ++g) { float w = wp[g]; c1 = fmaf(w, p1[g], c1); c2 = fmaf(w, p2[g], c2); }
    cpack[em * 1024 + f] = bfu(c1);
    cpack[em * 1024 + 64 + f] = bfu(c2);
    for (int r = 2; r < 16; ++r) cpack[em * 1024 + r * 64 + f] = 0;
  } else if (idx < 148480) {               // W1b = bf16(W_emb1) [64][1024]
    int j = idx - 132096;
    float4 v = ((const float4*)W_emb1)[j];
    ushort4 o; o.x = bfu(v.x); o.y = bfu(v.y); o.z = bfu(v.z); o.w = bfu(v.w);
    ((ushort4*)W1b)[j] = o;
  } else if (idx < 152576) {               // W2ab = bf16(W2a) [256][64]
    int j = idx - 148480;
    float4 v = ((const float4*)W2a)[j];
    ushort4 o; o.x = bfu(v.x); o.y = bfu(v.y); o.z = bfu(v.z); o.w = bfu(v.w);
    ((ushort4*)W2ab)[j] = o;
  } else if (idx < 156672) {               // W2bb = bf16(W2b) [64][256]
    int j = idx - 152576;
    float4 v = ((const float4*)W2b)[j];
    ushort4 o; o.x = bfu(v.x); o.y = bfu(v.y); o.z = bfu(v.z); o.w = bfu(v.w);
    ((ushort4*)W2bb)[j] = o;
  }
}

// ---------------- K1: MFMA Wh -> WhF (fragment-major) + s1/E2; PLUS A->bitmask --------------
// WhF layout: [bem][s 16][gb 4][lane 64][i 8] so a k2 wave loads one contiguous 1KB per instr.
__global__ void __launch_bounds__(256) k1_wh(const ush* __restrict__ Xb, const ush* __restrict__ WsT,
                                             const ush* __restrict__ cpack, const int* __restrict__ A,
                                             ush* __restrict__ WhF, float* __restrict__ s1,
                                             float2* __restrict__ E2, unsigned* __restrict__ Amask) {
  const int tid = threadIdx.x, lane = tid & 63, w = tid >> 6, c = lane & 15, grp = lane >> 4;
  const int blk = blockIdx.x, nt = blk & 7, em = (blk >> 3) & 15, b = blk >> 7;
  const int n0 = nt * 64, bem = b * 16 + em;

  // A -> bitmask: thread handles one 32-bit word; 128B contiguous read per thread.
  {
    const int w2 = blk * 256 + tid;                 // 0..262143  -> [be][i][c]
    const int* ap = A + (w2 >> 4) * 32 * 16 + (w2 & 15) * 32;
    unsigned bits = 0;
#pragma unroll
    for (int kq = 0; kq < 32; kq += 4) {
      int4 v = *(const int4*)(ap + kq);
      bits |= (v.x > 0 ? 1u : 0u) << kq;
      bits |= (v.y > 0 ? 1u : 0u) << (kq + 1);
      bits |= (v.z > 0 ? 1u : 0u) << (kq + 2);
      bits |= (v.w > 0 ? 1u : 0u) << (kq + 3);
    }
    Amask[w2] = bits;
  }

  f32x4 acc[4] = {};
  const ush* wsrow = WsT + em * 4096 + (w * 16 + c) * 64;
#pragma unroll
  for (int kk = 0; kk < 2; ++kk) {
    bf16x8 af = asbf(*(const int4*)(wsrow + kk * 32 + grp * 8));
#pragma unroll
    for (int t = 0; t < 4; ++t) {
      bf16x8 bv = asbf(*(const int4*)(Xb + (b * 512 + n0 + t * 16 + c) * 64 + kk * 32 + grp * 8));
      acc[t] = __builtin_amdgcn_mfma_f32_16x16x32_bf16(af, bv, acc[t], 0, 0, 0);
    }
  }
  // fragment-major scatter: element (g = w*16+grp*4+r, n = nt*64 + t*16 + c)
  //   s = nt*2 + (t>>1); grp' = (t&1)*2 + (c>>3); i = c&7; lane' = grp'*16 + (grp*4+r)
  ush* wout = WhF + bem * 32768;
#pragma unroll
  for (int t = 0; t < 4; ++t) {
    const int s  = nt * 2 + (t >> 1);
    const int gp = (t & 1) * 2 + (c >> 3);
    const int ii = c & 7;
#pragma unroll
    for (int r = 0; r < 4; ++r) {
      const int lane2 = gp * 16 + grp * 4 + r;
      wout[s * 2048 + w * 512 + lane2 * 8 + ii] = bfu(acc[t][r]);
    }
  }
  if (w == 0) {                            // s1 + E2=(exp(s2), exp(.01 s2)) via cpack MFMA
    f32x4 sacc[4] = {};
    const ush* crow = cpack + em * 1024 + c * 64;
#pragma unroll
    for (int kk = 0; kk < 2; ++kk) {
      bf16x8 af = asbf(*(const int4*)(crow + kk * 32 + grp * 8));
#pragma unroll
      for (int t = 0; t < 4; ++t) {
        bf16x8 bv = asbf(*(const int4*)(Xb + (b * 512 + n0 + t * 16 + c) * 64 + kk * 32 + grp * 8));
        sacc[t] = __builtin_amdgcn_mfma_f32_16x16x32_bf16(af, bv, sacc[t], 0, 0, 0);
      }
    }
    if (grp == 0) {
#pragma unroll
      for (int t = 0; t < 4; ++t) {
        float s2v = sacc[t][1];
        s1[bem * 512 + n0 + t * 16 + c] = sacc[t][0];
        E2[bem * 512 + n0 + t * 16 + c] = make_float2(__expf(s2v), __expf(0.01f * s2v));
      }
    }
  }
}

// ---------------- K2: factorized softmax + coalesced MFMA PV + ELU -> Hb bf16 -----------
// WhF loads are contiguous 1KB per wave-instruction; row-sums via ones-vector MFMA.
__global__ void __launch_bounds__(256) k2_attn(const unsigned* __restrict__ Amask,
                                               const ush* __restrict__ WhF,
                                               const float* __restrict__ s1,
                                               const float2* __restrict__ E2,
                                               ush* __restrict__ Hb) {
  const int tid = threadIdx.x, lane = tid & 63, m = tid >> 6;
  const int grp = lane >> 4, col = lane & 15;
  const int blk = blockIdx.x;
  const int xcd = blk & 7, kk2 = blk >> 3;
  const int be = xcd * 4 + (kk2 >> 5), itile = kk2 & 31;
  const int b = be >> 2, e = be & 3;
  const int i0 = itile * 16;
  const int bem = be * 4 + m;

  __shared__ unsigned maskw[16][17];
  __shared__ float2 e2l[4][512];     // 16KB: per-wave E2 row

  {  // 16x16 mask words (1KB, coalesced)
    const int row = tid >> 4, c = tid & 15;
    maskw[row][c] = Amask[(be * 512 + i0 + row) * 16 + c];
  }
  {  // stage E2[bem][0..511] into LDS
    const float2* e2g = E2 + bem * 512;
#pragma unroll
    for (int t = 0; t < 8; ++t) e2l[m][t * 64 + lane] = e2g[t * 64 + lane];
  }
  __syncthreads();

  const float s1row = s1[bem * N_ + i0 + col];
  const float e1p = __expf(s1row);
  const float e1n = __expf(0.01f * s1row);
  const float te  = __expf(-s1row);

  const ush* whb = WhF + bem * 32768 + lane * 8;
  f32x4 acc0 = {0.f, 0.f, 0.f, 0.f};
  f32x4 acc1 = acc0, acc2 = acc0, acc3 = acc0, accs = acc0;
  bf16x8 ones;
#pragma unroll
  for (int i = 0; i < 8; ++i) ones[i] = (__bf16)1.0f;

  // software-pipelined: preload s=0, then load s+1 while computing s.
  int4 c0 = *(const int4*)(whb + 0);
  int4 c1 = *(const int4*)(whb + 512);
  int4 c2 = *(const int4*)(whb + 1024);
  int4 c3 = *(const int4*)(whb + 1536);
#pragma unroll 4
  for (int s = 0; s < 16; ++s) {
    const int noff = ((s + 1) & 15) * 2048;        // s=15 wraps (harmless cached re-load)
    int4 n0 = *(const int4*)(whb + noff);
    int4 n1 = *(const int4*)(whb + noff + 512);
    int4 n2 = *(const int4*)(whb + noff + 1024);
    int4 n3 = *(const int4*)(whb + noff + 1536);

    unsigned mb = maskw[col][s] >> (grp * 8);
    const float2* ep = &e2l[m][s * 32 + grp * 8];
    bf16x8 af;
#pragma unroll
    for (int i = 0; i < 8; ++i) {
      float2 q = ep[i];
      float p = (q.x > te) ? q.x * e1p : q.y * e1n;
      p = ((mb >> i) & 1u) ? p : 0.f;
      af[i] = (__bf16)p;
    }
    accs = __builtin_amdgcn_mfma_f32_16x16x32_bf16(af, ones, accs, 0, 0, 0);
    acc0 = __builtin_amdgcn_mfma_f32_16x16x32_bf16(af, asbf(c0), acc0, 0, 0, 0);
    acc1 = __builtin_amdgcn_mfma_f32_16x16x32_bf16(af, asbf(c1), acc1, 0, 0, 0);
    acc2 = __builtin_amdgcn_mfma_f32_16x16x32_bf16(af, asbf(c2), acc2, 0, 0, 0);
    acc3 = __builtin_amdgcn_mfma_f32_16x16x32_bf16(af, asbf(c3), acc3, 0, 0, 0);
    c0 = n0; c1 = n1; c2 = n2; c3 = n3;
  }

  // accs[r] = row-sum of P for row grp*4+r (same value in every lane of the row group)
  ush* op = Hb + (b * N_ + i0 + grp * 4) * MEG + m * 256 + e * 64 + col;
#pragma unroll
  for (int r = 0; r < 4; ++r) {
    float sv2 = accs[r];
    float inv = sv2 > 0.f ? 1.f / sv2 : 0.f;
    float v0 = acc0[r] * inv; v0 = v0 > 0.f ? v0 : expm1f(v0);
    float v1 = acc1[r] * inv; v1 = v1 > 0.f ? v1 : expm1f(v1);
    float v2 = acc2[r] * inv; v2 = v2 > 0.f ? v2 : expm1f(v2);
    float v3 = acc3[r] * inv; v3 = v3 > 0.f ? v3 : expm1f(v3);
    op[r * MEG + 0]  = bfu(v0);
    op[r * MEG + 16] = bfu(v1);
    op[r * MEG + 32] = bfu(v2);
    op[r * MEG + 48] = bfu(v3);
  }
}

// ---------------- K3: MFMA  R = 0.5*(Hb @ W1b^T) + 0.5*X; partials P2R[blk][2][64] ----------------
__global__ void __launch_bounds__(256) k3_emb(const ush* __restrict__ Hb, const ush* __restrict__ W1b,
                                              const float* __restrict__ X, float* __restrict__ R,
                                              float* __restrict__ P2R) {
  const int tid = threadIdx.x, lane = tid & 63, w = tid >> 6, c = lane & 15, grp = lane >> 4;
  const int r0 = blockIdx.x * 16;
  const ush* ha = Hb + (r0 + c) * 1024 + grp * 8;
  const ush* wb = W1b + (w * 16 + c) * 1024 + grp * 8;
  f32x4 accA = {}, accB = {};      // 2 independent chains (break 32-deep MFMA dependency)
#pragma unroll 8
  for (int kk = 0; kk < 32; kk += 2) {
    accA = __builtin_amdgcn_mfma_f32_16x16x32_bf16(asbf(*(const int4*)(ha + kk * 32)),
                                                   asbf(*(const int4*)(wb + kk * 32)), accA, 0, 0, 0);
    accB = __builtin_amdgcn_mfma_f32_16x16x32_bf16(asbf(*(const int4*)(ha + kk * 32 + 32)),
                                                   asbf(*(const int4*)(wb + kk * 32 + 32)), accB, 0, 0, 0);
  }
  f32x4 acc = accA + accB;
  const int col = w * 16 + c;
  float s = 0.f, q = 0.f;
#pragma unroll
  for (int r = 0; r < 4; ++r) {
    int row = r0 + grp * 4 + r;
    float v = 0.5f * acc[r] + 0.5f * X[row * 64 + col];
    R[row * 64 + col] = v;
    s += v; q = fmaf(v, v, q);
  }
  s += __shfl_xor(s, 16); s += __shfl_xor(s, 32);
  q += __shfl_xor(q, 16); q += __shfl_xor(q, 32);
  if (grp == 0) { P2R[blockIdx.x * 128 + col] = s; P2R[blockIdx.x * 128 + 64 + col] = q; }
}

// ---------------- K4: reduce P2R -> muR/rsR (per block); T = BN(R) @ W2a^T; P2T[blk][2][256] ----
__global__ void __launch_bounds__(256) k4_node1(const float* __restrict__ R, const float* __restrict__ P2R,
                                                const ush* __restrict__ W2ab,
                                                float* __restrict__ T, float* __restrict__ P2T) {
  const int tid = threadIdx.x, lane = tid & 63, w = tid >> 6, c = lane & 15, grp = lane >> 4;
  const int r0 = blockIdx.x * 16, cb = w * 64;
  __shared__ float muR[64], rsR[64];
  if (tid < 128) {
    const int cc = tid & 63;
    float a = 0.f;
    for (int bk = 0; bk < 256; ++bk) a += P2R[bk * 128 + tid];
    if (tid < 64) muR[cc] = a * (1.f / 4096.f); else rsR[cc] = a;
  }
  __syncthreads();
  if (tid < 64) {
    float m = muR[tid];
    float v = rsR[tid] * (1.f / 4096.f) - m * m;
    rsR[tid] = rsqrtf(v + 1e-5f);
  }
  __syncthreads();

  f32x4 acc[4] = {};
#pragma unroll
  for (int kk = 0; kk < 2; ++kk) {
    const float* rp = R + (r0 + c) * 64 + kk * 32 + grp * 8;
    float4 v0 = *(const float4*)rp;
    float4 v1 = *(const float4*)(rp + 4);
    float vv[8] = {v0.x, v0.y, v0.z, v0.w, v1.x, v1.y, v1.z, v1.w};
    bf16x8 af;
#pragma unroll
    for (int i = 0; i < 8; ++i) {
      int f = kk * 32 + grp * 8 + i;
      af[i] = (__bf16)((vv[i] - muR[f]) * rsR[f]);
    }
#pragma unroll
    for (int ct = 0; ct < 4; ++ct) {
      bf16x8 bv = asbf(*(const int4*)(W2ab + (cb + ct * 16 + c) * 64 + kk * 32 + grp * 8));
      acc[ct] = __builtin_amdgcn_mfma_f32_16x16x32_bf16(af, bv, acc[ct], 0, 0, 0);
    }
  }
#pragma unroll
  for (int ct = 0; ct < 4; ++ct) {
    const int col = cb + ct * 16 + c;
    float s = 0.f, q = 0.f;
#pragma unroll
    for (int r = 0; r < 4; ++r) {
      float v = acc[ct][r];
      T[(r0 + grp * 4 + r) * 256 + col] = v;
      s += v; q = fmaf(v, v, q);
    }
    s += __shfl_xor(s, 16); s += __shfl_xor(s, 32);
    q += __shfl_xor(q, 16); q += __shfl_xor(q, 32);
    if (grp == 0) { P2T[blockIdx.x * 512 + col] = s; P2T[blockIdx.x * 512 + 256 + col] = q; }
  }
}

// ---------------- K5: reduce P2T,P2R; S = BN_R(R) + ELU(BN(T)) @ W2b^T; P2S[blk][2][64] ----------
__global__ void __launch_bounds__(256) k5_node2(const float* __restrict__ T, const float* __restrict__ P2T,
                                                const ush* __restrict__ W2bb,
                                                const float* __restrict__ R, const float* __restrict__ P2R,
                                                float* __restrict__ S, float* __restrict__ P2S) {
  const int tid = threadIdx.x, lane = tid & 63, w = tid >> 6, c = lane & 15, grp = lane >> 4;
  const int r0 = blockIdx.x * 16;
  __shared__ float muT[256], rsT[256], muR[64], rsR[64];
  {
    float s = 0.f, q = 0.f;
    for (int bk = 0; bk < 256; ++bk) {
      s += P2T[bk * 512 + tid];
      q += P2T[bk * 512 + 256 + tid];
    }
    float m = s * (1.f / 4096.f);
    float v = q * (1.f / 4096.f) - m * m;
    muT[tid] = m; rsT[tid] = rsqrtf(v + 1e-5f);
  }
  if (tid < 128) {
    const int cc = tid & 63;
    float a = 0.f;
    for (int bk = 0; bk < 256; ++bk) a += P2R[bk * 128 + tid];
    if (tid < 64) muR[cc] = a * (1.f / 4096.f); else rsR[cc] = a;
  }
  __syncthreads();
  if (tid < 64) {
    float m = muR[tid];
    float v = rsR[tid] * (1.f / 4096.f) - m * m;
    rsR[tid] = rsqrtf(v + 1e-5f);
  }
  __syncthreads();

  f32x4 accA = {}, accB = {};       // 2 independent chains
  const ush* wrow = W2bb + (w * 16 + c) * 256 + grp * 8;
  const float* trow = T + (r0 + c) * 256 + grp * 8;
#pragma unroll
  for (int kk = 0; kk < 8; ++kk) {
    float4 v0 = *(const float4*)(trow + kk * 32);
    float4 v1 = *(const float4*)(trow + kk * 32 + 4);
    float vv[8] = {v0.x, v0.y, v0.z, v0.w, v1.x, v1.y, v1.z, v1.w};
    bf16x8 af;
#pragma unroll
    for (int i = 0; i < 8; ++i) {
      int u = kk * 32 + grp * 8 + i;
      float t = (vv[i] - muT[u]) * rsT[u];
      t = t > 0.f ? t : expm1f(t);
      af[i] = (__bf16)t;
    }
    bf16x8 bv = asbf(*(const int4*)(wrow + kk * 32));
    if (kk & 1) accB = __builtin_amdgcn_mfma_f32_16x16x32_bf16(af, bv, accB, 0, 0, 0);
    else        accA = __builtin_amdgcn_mfma_f32_16x16x32_bf16(af, bv, accA, 0, 0, 0);
  }
  f32x4 acc = accA + accB;
  const int col = w * 16 + c;
  const float mu = muR[col], rsv = rsR[col];
  float s = 0.f, q = 0.f;
#pragma unroll
  for (int r = 0; r < 4; ++r) {
    int row = r0 + grp * 4 + r;
    float v = acc[r] + (R[row * 64 + col] - mu) * rsv;
    S[row * 64 + col] = v;
    s += v; q = fmaf(v, v, q);
  }
  s += __shfl_xor(s, 16); s += __shfl_xor(s, 32);
  q += __shfl_xor(q, 16); q += __shfl_xor(q, 32);
  if (grp == 0) { P2S[blockIdx.x * 128 + col] = s; P2S[blockIdx.x * 128 + 64 + col] = q; }
}

// ---------------- K6: reduce P2S; out = BN(S) ----------------
__global__ void __launch_bounds__(256) k6_bn(const float* __restrict__ S, const float* __restrict__ P2S,
                                             float* __restrict__ out) {
  const int tid = threadIdx.x;
  const int r0 = blockIdx.x * 16;
  __shared__ float muS[64], rsS[64];
  if (tid < 128) {
    const int cc = tid & 63;
    float a = 0.f;
    for (int bk = 0; bk < 256; ++bk) a += P2S[bk * 128 + tid];
    if (tid < 64) muS[cc] = a * (1.f / 4096.f); else rsS[cc] = a;
  }
  __syncthreads();
  if (tid < 64) {
    float m = muS[tid];
    float v = rsS[tid] * (1.f / 4096.f) - m * m;
    rsS[tid] = rsqrtf(v + 1e-5f);
  }
  __syncthreads();
  const int f0 = (tid * 4) & 63;
  float4 v = *(const float4*)(S + r0 * 64 + tid * 4);
  float4 o;
  o.x = (v.x - muS[f0 + 0]) * rsS[f0 + 0];
  o.y = (v.y - muS[f0 + 1]) * rsS[f0 + 1];
  o.z = (v.z - muS[f0 + 2]) * rsS[f0 + 2];
  o.w = (v.w - muS[f0 + 3]) * rsS[f0 + 3];
  *(float4*)(out + r0 * 64 + tid * 4) = o;
}

extern "C" void kernel_launch(void* const* d_in, const int* in_sizes, int n_in,
                              void* d_out, int out_size, void* d_ws, size_t ws_size,
                              hipStream_t stream) {
  const int*   A      = (const int*)d_in[0];
  const float* X      = (const float*)d_in[1];
  const float* Ws     = (const float*)d_in[2];
  const float* a1     = (const float*)d_in[3];
  const float* a2     = (const float*)d_in[4];
  const float* W_emb1 = (const float*)d_in[5];
  const float* W2a    = (const float*)d_in[6];
  const float* W2b    = (const float*)d_in[7];
  float* out = (float*)d_out;

  float* ws = (float*)d_ws;
  ush*   Hb    = (ush*)d_ws;                 // [4096][1024] bf16   (2,097,152 fl)
  ush*   WhF   = (ush*)(ws + 2097152);       // [128][16][4][64][8] bf16 (2,097,152 fl)
  float* s1    = ws + 4194304;               // 65,536
  float2* E2   = (float2*)(ws + 4259840);    // [128][512] float2 = 131,072 fl
  ush*   Xb    = (ush*)(ws + 4390912);       // 131,072 fl
  ush*   WsT   = (ush*)(ws + 4521984);       // 32,768 fl
  ush*   cpack = (ush*)(ws + 4554752);       // 8,192 fl
  ush*   W1b   = (ush*)(ws + 4562944);       // 32,768 fl
  ush*   W2ab  = (ush*)(ws + 4595712);       // 8,192 fl
  ush*   W2bb  = (ush*)(ws + 4603904);       // 8,192 fl
  float* R     = ws + 4612096;               // 262,144
  float* T     = ws + 4874240;               // 1,048,576
  float* S     = ws + 5922816;               // 262,144
  float* P2R   = ws + 6184960;               // 32,768  [256][2][64]
  float* P2T   = ws + 6217728;               // 131,072 [256][2][256]
  float* P2S   = ws + 6348800;               // 32,768  [256][2][64]  (end ~25.5 MB)
  // Amask [32 be][512 i][16 c] uint = 262,144 words; aliases R (R written only in k3,
  // after k2 has consumed Amask).
  unsigned* Amask = (unsigned*)R;

  kprep<<<612, 256, 0, stream>>>(X, Ws, a1, a2, W_emb1, W2a, W2b, Xb, WsT, cpack, W1b, W2ab, W2bb);
  k1_wh<<<1024, 256, 0, stream>>>(Xb, WsT, cpack, A, WhF, s1, E2, Amask);
  k2_attn<<<1024, 256, 0, stream>>>(Amask, WhF, s1, E2, Hb);
  k3_emb<<<256, 256, 0, stream>>>(Hb, W1b, X, R, P2R);
  k4_node1<<<256, 256, 0, stream>>>(R, P2R, W2ab, T, P2T);
  k5_node2<<<256, 256, 0, stream>>>(T, P2T, W2bb, R, P2R, S, P2S);
  k6_bn<<<256, 256, 0, stream>>>(S, P2S, out);
}

// Round 12
// 96.709 us; speedup vs baseline: 1.6606x; 1.0041x over previous
//
#include <hip/hip_runtime.h>
#include <math.h>

#define B_   8
#define N_   512
#define F_   64
#define G_   64
#define M_   4
#define E_   4
#define MEG  1024

typedef __attribute__((ext_vector_type(8))) __bf16 bf16x8;
typedef __attribute__((ext_vector_type(4))) float f32x4;
typedef unsigned short ush;

static __device__ __forceinline__ ush bfu(float x) { __bf16 h = (__bf16)x; return __builtin_bit_cast(ush, h); }
static __device__ __forceinline__ bf16x8 asbf(int4 v) { return __builtin_bit_cast(bf16x8, v); }
static __device__ __forceinline__ bf16x8 cvt8(float4 a, float4 b) {
  bf16x8 r;
  r[0] = (__bf16)a.x; r[1] = (__bf16)a.y; r[2] = (__bf16)a.z; r[3] = (__bf16)a.w;
  r[4] = (__bf16)b.x; r[5] = (__bf16)b.y; r[6] = (__bf16)b.z; r[7] = (__bf16)b.w;
  return r;
}

// ---------------- K1 (self-staged): MFMA Wh -> WhF fragment-major + s1/E2 + A->bitmask ------
// LDS-stages X and Ws[em] in fragment-major order; computes c1/c2 = Ws@a1/a2 in-block.
__global__ void __launch_bounds__(256) k1_wh(const float* __restrict__ X, const float* __restrict__ Ws,
                                             const float* __restrict__ a1, const float* __restrict__ a2,
                                             const int* __restrict__ A,
                                             ush* __restrict__ WhF, float* __restrict__ s1,
                                             float2* __restrict__ E2, unsigned* __restrict__ Amask) {
  const int tid = threadIdx.x, lane = tid & 63, w = tid >> 6, c = lane & 15, grp = lane >> 4;
  const int blk = blockIdx.x, nt = blk & 7, em = (blk >> 3) & 15, b = blk >> 7;
  const int n0 = nt * 64, bem = b * 16 + em;

  __shared__ __align__(16) ush xl[2][4][64][8];   // [kk][t][lane][i]  8KB  (X fragments)
  __shared__ __align__(16) ush wl[2][4][64][8];   // [kk][w][lane][i]  8KB  (WsT fragments)
  __shared__ float c1b[64], c2b[64];
  __shared__ __align__(16) ush st[4096];          // WhF store staging 8KB

  // A -> bitmask: one 32-bit word per thread; 128B contiguous read.
  {
    const int w2 = blk * 256 + tid;               // [be][i][cword]
    const int* ap = A + (w2 >> 4) * 512 + (w2 & 15) * 32;
    unsigned bits = 0;
#pragma unroll
    for (int kq = 0; kq < 32; kq += 4) {
      int4 v = *(const int4*)(ap + kq);
      bits |= (v.x > 0 ? 1u : 0u) << kq;
      bits |= (v.y > 0 ? 1u : 0u) << (kq + 1);
      bits |= (v.z > 0 ? 1u : 0u) << (kq + 2);
      bits |= (v.w > 0 ? 1u : 0u) << (kq + 3);
    }
    Amask[w2] = bits;
  }

  // stage X rows [n0, n0+64) -> fragment-major bf16
  {
    const int row = tid >> 2, cg = tid & 3;
    const int t = row >> 4, cc = row & 15;
    const float* xp = X + (b * 512 + n0 + row) * 64 + cg * 16;
#pragma unroll
    for (int q4 = 0; q4 < 4; ++q4) {
      float4 v = ((const float4*)xp)[q4];
      float vals[4] = {v.x, v.y, v.z, v.w};
#pragma unroll
      for (int u = 0; u < 4; ++u) {
        const int f = cg * 16 + q4 * 4 + u;
        xl[f >> 5][t][((f >> 3) & 3) * 16 + cc][f & 7] = bfu(vals[u]);
      }
    }
  }
  // stage Ws[em] transposed fragment-major + c1/c2 partial dots
  {
    const int f = tid >> 2, gq = tid & 3;
    const int kk = f >> 5, gg = (f >> 3) & 3, ii = f & 7;
    const float* wp = Ws + em * 4096 + f * 64 + gq * 16;
    const float* p1 = a1 + em * 64 + gq * 16;
    const float* p2 = a2 + em * 64 + gq * 16;
    float d1 = 0.f, d2 = 0.f;
#pragma unroll
    for (int q4 = 0; q4 < 4; ++q4) {
      float4 v  = ((const float4*)wp)[q4];
      float4 va = ((const float4*)p1)[q4];
      float4 vb = ((const float4*)p2)[q4];
      float vals[4] = {v.x, v.y, v.z, v.w};
      float aa[4] = {va.x, va.y, va.z, va.w};
      float bb[4] = {vb.x, vb.y, vb.z, vb.w};
#pragma unroll
      for (int u = 0; u < 4; ++u) {
        const int g = gq * 16 + q4 * 4 + u;
        wl[kk][g >> 4][gg * 16 + (g & 15)][ii] = bfu(vals[u]);
        d1 = fmaf(vals[u], aa[u], d1);
        d2 = fmaf(vals[u], bb[u], d2);
      }
    }
    d1 += __shfl_xor(d1, 1); d1 += __shfl_xor(d1, 2);
    d2 += __shfl_xor(d2, 1); d2 += __shfl_xor(d2, 2);
    if (gq == 0) { c1b[f] = d1; c2b[f] = d2; }
  }
  __syncthreads();

  f32x4 acc[4] = {};
#pragma unroll
  for (int kk = 0; kk < 2; ++kk) {
    bf16x8 af = asbf(*(const int4*)&wl[kk][w][lane][0]);
#pragma unroll
    for (int t = 0; t < 4; ++t) {
      bf16x8 bv = asbf(*(const int4*)&xl[kk][t][lane][0]);
      acc[t] = __builtin_amdgcn_mfma_f32_16x16x32_bf16(af, bv, acc[t], 0, 0, 0);
    }
  }
  // fragment-major store staging (same mapping as validated R10 k1)
#pragma unroll
  for (int t = 0; t < 4; ++t) {
    const int sl = t >> 1;
    const int gp = (t & 1) * 2 + (c >> 3);
    const int ii = c & 7;
#pragma unroll
    for (int r = 0; r < 4; ++r)
      st[sl * 2048 + w * 512 + (gp * 16 + grp * 4 + r) * 8 + ii] = bfu(acc[t][r]);
  }
  if (w == 0) {                            // s1 + E2 via c1/c2 MFMA rows 0,1
    f32x4 sacc[4] = {};
#pragma unroll
    for (int kk = 0; kk < 2; ++kk) {
      bf16x8 af;
#pragma unroll
      for (int i = 0; i < 8; ++i) {
        const int f = kk * 32 + grp * 8 + i;
        float v = (c == 0) ? c1b[f] : (c == 1) ? c2b[f] : 0.f;
        af[i] = (__bf16)v;
      }
#pragma unroll
      for (int t = 0; t < 4; ++t) {
        bf16x8 bv = asbf(*(const int4*)&xl[kk][t][lane][0]);
        sacc[t] = __builtin_amdgcn_mfma_f32_16x16x32_bf16(af, bv, sacc[t], 0, 0, 0);
      }
    }
    if (grp == 0) {
#pragma unroll
      for (int t = 0; t < 4; ++t) {
        float s2v = sacc[t][1];
        s1[bem * 512 + n0 + t * 16 + c] = sacc[t][0];
        E2[bem * 512 + n0 + t * 16 + c] = make_float2(__expf(s2v), __expf(0.01f * s2v));
      }
    }
  }
  __syncthreads();
  {  // coalesced copy-out: 4096 ush = 2 int4 per thread
    int4* dst = (int4*)(WhF + bem * 32768 + nt * 4096);
    const int4* src = (const int4*)st;
    dst[tid * 2]     = src[tid * 2];
    dst[tid * 2 + 1] = src[tid * 2 + 1];
  }
}

// ---------------- K2: factorized softmax + coalesced MFMA PV + ELU -> Hb bf16 -----------
__global__ void __launch_bounds__(256) k2_attn(const unsigned* __restrict__ Amask,
                                               const ush* __restrict__ WhF,
                                               const float* __restrict__ s1,
                                               const float2* __restrict__ E2,
                                               ush* __restrict__ Hb) {
  const int tid = threadIdx.x, lane = tid & 63, m = tid >> 6;
  const int grp = lane >> 4, col = lane & 15;
  const int blk = blockIdx.x;
  const int xcd = blk & 7, kk2 = blk >> 3;
  const int be = xcd * 4 + (kk2 >> 5), itile = kk2 & 31;
  const int b = be >> 2, e = be & 3;
  const int i0 = itile * 16;
  const int bem = be * 4 + m;

  __shared__ unsigned maskw[16][17];
  __shared__ float2 e2l[4][512];

  {
    const int row = tid >> 4, cc = tid & 15;
    maskw[row][cc] = Amask[(be * 512 + i0 + row) * 16 + cc];
  }
  {
    const float2* e2g = E2 + bem * 512;
#pragma unroll
    for (int t = 0; t < 8; ++t) e2l[m][t * 64 + lane] = e2g[t * 64 + lane];
  }
  __syncthreads();

  const float s1row = s1[bem * N_ + i0 + col];
  const float e1p = __expf(s1row);
  const float e1n = __expf(0.01f * s1row);
  const float te  = __expf(-s1row);

  const ush* whb = WhF + bem * 32768 + lane * 8;
  f32x4 acc0 = {0.f, 0.f, 0.f, 0.f};
  f32x4 acc1 = acc0, acc2 = acc0, acc3 = acc0, accs = acc0;
  bf16x8 ones;
#pragma unroll
  for (int i = 0; i < 8; ++i) ones[i] = (__bf16)1.0f;

  int4 c0 = *(const int4*)(whb + 0);
  int4 c1 = *(const int4*)(whb + 512);
  int4 c2 = *(const int4*)(whb + 1024);
  int4 c3 = *(const int4*)(whb + 1536);
#pragma unroll 4
  for (int s = 0; s < 16; ++s) {
    const int noff = ((s + 1) & 15) * 2048;
    int4 n0 = *(const int4*)(whb + noff);
    int4 n1 = *(const int4*)(whb + noff + 512);
    int4 n2 = *(const int4*)(whb + noff + 1024);
    int4 n3 = *(const int4*)(whb + noff + 1536);

    unsigned mb = maskw[col][s] >> (grp * 8);
    const float2* ep = &e2l[m][s * 32 + grp * 8];
    bf16x8 af;
#pragma unroll
    for (int i = 0; i < 8; ++i) {
      float2 q = ep[i];
      float p = (q.x > te) ? q.x * e1p : q.y * e1n;
      p = ((mb >> i) & 1u) ? p : 0.f;
      af[i] = (__bf16)p;
    }
    accs = __builtin_amdgcn_mfma_f32_16x16x32_bf16(af, ones, accs, 0, 0, 0);
    acc0 = __builtin_amdgcn_mfma_f32_16x16x32_bf16(af, asbf(c0), acc0, 0, 0, 0);
    acc1 = __builtin_amdgcn_mfma_f32_16x16x32_bf16(af, asbf(c1), acc1, 0, 0, 0);
    acc2 = __builtin_amdgcn_mfma_f32_16x16x32_bf16(af, asbf(c2), acc2, 0, 0, 0);
    acc3 = __builtin_amdgcn_mfma_f32_16x16x32_bf16(af, asbf(c3), acc3, 0, 0, 0);
    c0 = n0; c1 = n1; c2 = n2; c3 = n3;
  }

  ush* op = Hb + (b * N_ + i0 + grp * 4) * MEG + m * 256 + e * 64 + col;
#pragma unroll
  for (int r = 0; r < 4; ++r) {
    float sv2 = accs[r];
    float inv = sv2 > 0.f ? 1.f / sv2 : 0.f;
    float v0 = acc0[r] * inv; v0 = v0 > 0.f ? v0 : expm1f(v0);
    float v1 = acc1[r] * inv; v1 = v1 > 0.f ? v1 : expm1f(v1);
    float v2 = acc2[r] * inv; v2 = v2 > 0.f ? v2 : expm1f(v2);
    float v3 = acc3[r] * inv; v3 = v3 > 0.f ? v3 : expm1f(v3);
    op[r * MEG + 0]  = bfu(v0);
    op[r * MEG + 16] = bfu(v1);
    op[r * MEG + 32] = bfu(v2);
    op[r * MEG + 48] = bfu(v3);
  }
}

// ---------------- K3: MFMA  R = 0.5*(Hb @ W_emb1^T) + 0.5*X; partials P2R[blk][2][64] -------
__global__ void __launch_bounds__(256) k3_emb(const ush* __restrict__ Hb, const float* __restrict__ W_emb1,
                                              const float* __restrict__ X, float* __restrict__ R,
                                              float* __restrict__ P2R) {
  const int tid = threadIdx.x, lane = tid & 63, w = tid >> 6, c = lane & 15, grp = lane >> 4;
  const int r0 = blockIdx.x * 16;
  const ush* ha = Hb + (r0 + c) * 1024 + grp * 8;
  const float* wbf = W_emb1 + (w * 16 + c) * 1024 + grp * 8;
  f32x4 accA = {}, accB = {};
#pragma unroll 8
  for (int kk = 0; kk < 32; kk += 2) {
    bf16x8 w0 = cvt8(*(const float4*)(wbf + kk * 32),      *(const float4*)(wbf + kk * 32 + 4));
    bf16x8 w1 = cvt8(*(const float4*)(wbf + kk * 32 + 32), *(const float4*)(wbf + kk * 32 + 36));
    accA = __builtin_amdgcn_mfma_f32_16x16x32_bf16(asbf(*(const int4*)(ha + kk * 32)), w0, accA, 0, 0, 0);
    accB = __builtin_amdgcn_mfma_f32_16x16x32_bf16(asbf(*(const int4*)(ha + kk * 32 + 32)), w1, accB, 0, 0, 0);
  }
  f32x4 acc = accA + accB;
  const int col = w * 16 + c;
  float s = 0.f, q = 0.f;
#pragma unroll
  for (int r = 0; r < 4; ++r) {
    int row = r0 + grp * 4 + r;
    float v = 0.5f * acc[r] + 0.5f * X[row * 64 + col];
    R[row * 64 + col] = v;
    s += v; q = fmaf(v, v, q);
  }
  s += __shfl_xor(s, 16); s += __shfl_xor(s, 32);
  q += __shfl_xor(q, 16); q += __shfl_xor(q, 32);
  if (grp == 0) { P2R[blockIdx.x * 128 + col] = s; P2R[blockIdx.x * 128 + 64 + col] = q; }
}

// ---------------- K4: reduce P2R; T = BN(R) @ W2a^T; P2T[blk][2][256] ----
__global__ void __launch_bounds__(256) k4_node1(const float* __restrict__ R, const float* __restrict__ P2R,
                                                const float* __restrict__ W2a,
                                                float* __restrict__ T, float* __restrict__ P2T) {
  const int tid = threadIdx.x, lane = tid & 63, w = tid >> 6, c = lane & 15, grp = lane >> 4;
  const int r0 = blockIdx.x * 16, cb = w * 64;
  __shared__ float muR[64], rsR[64];
  if (tid < 128) {
    const int cc = tid & 63;
    float a = 0.f;
    for (int bk = 0; bk < 256; ++bk) a += P2R[bk * 128 + tid];
    if (tid < 64) muR[cc] = a * (1.f / 4096.f); else rsR[cc] = a;
  }
  __syncthreads();
  if (tid < 64) {
    float m = muR[tid];
    float v = rsR[tid] * (1.f / 4096.f) - m * m;
    rsR[tid] = rsqrtf(v + 1e-5f);
  }
  __syncthreads();

  f32x4 acc[4] = {};
#pragma unroll
  for (int kk = 0; kk < 2; ++kk) {
    const float* rp = R + (r0 + c) * 64 + kk * 32 + grp * 8;
    float4 v0 = *(const float4*)rp;
    float4 v1 = *(const float4*)(rp + 4);
    float vv[8] = {v0.x, v0.y, v0.z, v0.w, v1.x, v1.y, v1.z, v1.w};
    bf16x8 af;
#pragma unroll
    for (int i = 0; i < 8; ++i) {
      int f = kk * 32 + grp * 8 + i;
      af[i] = (__bf16)((vv[i] - muR[f]) * rsR[f]);
    }
#pragma unroll
    for (int ct = 0; ct < 4; ++ct) {
      const float* wp = W2a + (cb + ct * 16 + c) * 64 + kk * 32 + grp * 8;
      bf16x8 bv = cvt8(*(const float4*)wp, *(const float4*)(wp + 4));
      acc[ct] = __builtin_amdgcn_mfma_f32_16x16x32_bf16(af, bv, acc[ct], 0, 0, 0);
    }
  }
#pragma unroll
  for (int ct = 0; ct < 4; ++ct) {
    const int col = cb + ct * 16 + c;
    float s = 0.f, q = 0.f;
#pragma unroll
    for (int r = 0; r < 4; ++r) {
      float v = acc[ct][r];
      T[(r0 + grp * 4 + r) * 256 + col] = v;
      s += v; q = fmaf(v, v, q);
    }
    s += __shfl_xor(s, 16); s += __shfl_xor(s, 32);
    q += __shfl_xor(q, 16); q += __shfl_xor(q, 32);
    if (grp == 0) { P2T[blockIdx.x * 512 + col] = s; P2T[blockIdx.x * 512 + 256 + col] = q; }
  }
}

// ---------------- K5: reduce P2T,P2R; S = BN_R(R) + ELU(BN(T)) @ W2b^T; P2S[blk][2][64] ------
__global__ void __launch_bounds__(256) k5_node2(const float* __restrict__ T, const float* __restrict__ P2T,
                                                const float* __restrict__ W2b,
                                                const float* __restrict__ R, const float* __restrict__ P2R,
                                                float* __restrict__ S, float* __restrict__ P2S) {
  const int tid = threadIdx.x, lane = tid & 63, w = tid >> 6, c = lane & 15, grp = lane >> 4;
  const int r0 = blockIdx.x * 16;
  __shared__ float muT[256], rsT[256], muR[64], rsR[64];
  {
    float s = 0.f, q = 0.f;
    for (int bk = 0; bk < 256; ++bk) {
      s += P2T[bk * 512 + tid];
      q += P2T[bk * 512 + 256 + tid];
    }
    float m = s * (1.f / 4096.f);
    float v = q * (1.f / 4096.f) - m * m;
    muT[tid] = m; rsT[tid] = rsqrtf(v + 1e-5f);
  }
  if (tid < 128) {
    const int cc = tid & 63;
    float a = 0.f;
    for (int bk = 0; bk < 256; ++bk) a += P2R[bk * 128 + tid];
    if (tid < 64) muR[cc] = a * (1.f / 4096.f); else rsR[cc] = a;
  }
  __syncthreads();
  if (tid < 64) {
    float m = muR[tid];
    float v = rsR[tid] * (1.f / 4096.f) - m * m;
    rsR[tid] = rsqrtf(v + 1e-5f);
  }
  __syncthreads();

  f32x4 accA = {}, accB = {};
  const float* wrow = W2b + (w * 16 + c) * 256 + grp * 8;
  const float* trow = T + (r0 + c) * 256 + grp * 8;
#pragma unroll
  for (int kk = 0; kk < 8; ++kk) {
    float4 v0 = *(const float4*)(trow + kk * 32);
    float4 v1 = *(const float4*)(trow + kk * 32 + 4);
    float vv[8] = {v0.x, v0.y, v0.z, v0.w, v1.x, v1.y, v1.z, v1.w};
    bf16x8 af;
#pragma unroll
    for (int i = 0; i < 8; ++i) {
      int u = kk * 32 + grp * 8 + i;
      float t = (vv[i] - muT[u]) * rsT[u];
      t = t > 0.f ? t : expm1f(t);
      af[i] = (__bf16)t;
    }
    bf16x8 bv = cvt8(*(const float4*)(wrow + kk * 32), *(const float4*)(wrow + kk * 32 + 4));
    if (kk & 1) accB = __builtin_amdgcn_mfma_f32_16x16x32_bf16(af, bv, accB, 0, 0, 0);
    else        accA = __builtin_amdgcn_mfma_f32_16x16x32_bf16(af, bv, accA, 0, 0, 0);
  }
  f32x4 acc = accA + accB;
  const int col = w * 16 + c;
  const float mu = muR[col], rsv = rsR[col];
  float s = 0.f, q = 0.f;
#pragma unroll
  for (int r = 0; r < 4; ++r) {
    int row = r0 + grp * 4 + r;
    float v = acc[r] + (R[row * 64 + col] - mu) * rsv;
    S[row * 64 + col] = v;
    s += v; q = fmaf(v, v, q);
  }
  s += __shfl_xor(s, 16); s += __shfl_xor(s, 32);
  q += __shfl_xor(q, 16); q += __shfl_xor(q, 32);
  if (grp == 0) { P2S[blockIdx.x * 128 + col] = s; P2S[blockIdx.x * 128 + 64 + col] = q; }
}

// ---------------- K6: reduce P2S; out = BN(S) ----------------
__global__ void __launch_bounds__(256) k6_bn(const float* __restrict__ S, const float* __restrict__ P2S,
                                             float* __restrict__ out) {
  const int tid = threadIdx.x;
  const int r0 = blockIdx.x * 16;
  __shared__ float muS[64], rsS[64];
  if (tid < 128) {
    const int cc = tid & 63;
    float a = 0.f;
    for (int bk = 0; bk < 256; ++bk) a += P2S[bk * 128 + tid];
    if (tid < 64) muS[cc] = a * (1.f / 4096.f); else rsS[cc] = a;
  }
  __syncthreads();
  if (tid < 64) {
    float m = muS[tid];
    float v = rsS[tid] * (1.f / 4096.f) - m * m;
    rsS[tid] = rsqrtf(v + 1e-5f);
  }
  __syncthreads();
  const int f0 = (tid * 4) & 63;
  float4 v = *(const float4*)(S + r0 * 64 + tid * 4);
  float4 o;
  o.x = (v.x - muS[f0 + 0]) * rsS[f0 + 0];
  o.y = (v.y - muS[f0 + 1]) * rsS[f0 + 1];
  o.z = (v.z - muS[f0 + 2]) * rsS[f0 + 2];
  o.w = (v.w - muS[f0 + 3]) * rsS[f0 + 3];
  *(float4*)(out + r0 * 64 + tid * 4) = o;
}

extern "C" void kernel_launch(void* const* d_in, const int* in_sizes, int n_in,
                              void* d_out, int out_size, void* d_ws, size_t ws_size,
                              hipStream_t stream) {
  const int*   A      = (const int*)d_in[0];
  const float* X      = (const float*)d_in[1];
  const float* Ws     = (const float*)d_in[2];
  const float* a1     = (const float*)d_in[3];
  const float* a2     = (const float*)d_in[4];
  const float* W_emb1 = (const float*)d_in[5];
  const float* W2a    = (const float*)d_in[6];
  const float* W2b    = (const float*)d_in[7];
  float* out = (float*)d_out;

  float* ws = (float*)d_ws;
  ush*   Hb    = (ush*)d_ws;                 // [4096][1024] bf16   (2,097,152 fl)
  ush*   WhF   = (ush*)(ws + 2097152);       // [128][16][4][64][8] bf16 (2,097,152 fl)
  float* s1    = ws + 4194304;               // 65,536
  float2* E2   = (float2*)(ws + 4259840);    // [128][512] float2 = 131,072 fl
  float* R     = ws + 4612096;               // 262,144
  float* T     = ws + 4874240;               // 1,048,576
  float* S     = ws + 5922816;               // 262,144
  float* P2R   = ws + 6184960;               // 32,768  [256][2][64]
  float* P2T   = ws + 6217728;               // 131,072 [256][2][256]
  float* P2S   = ws + 6348800;               // 32,768  [256][2][64]  (end ~25.5 MB)
  // Amask [32 be][512 i][16 c] uint aliases R (k1 writes, k2 reads, k3 overwrites R later).
  unsigned* Amask = (unsigned*)R;

  k1_wh<<<1024, 256, 0, stream>>>(X, Ws, a1, a2, A, WhF, s1, E2, Amask);
  k2_attn<<<1024, 256, 0, stream>>>(Amask, WhF, s1, E2, Hb);
  k3_emb<<<256, 256, 0, stream>>>(Hb, W_emb1, X, R, P2R);
  k4_node1<<<256, 256, 0, stream>>>(R, P2R, W2a, T, P2T);
  k5_node2<<<256, 256, 0, stream>>>(T, P2T, W2b, R, P2R, S, P2S);
  k6_bn<<<256, 256, 0, stream>>>(S, P2S, out);
}